// Round 1
// baseline (4101.751 us; speedup 1.0000x reference)
//
#include <hip/hip_runtime.h>
#include <cstddef>
#include <cstdint>

// Problem constants (match reference)
constexpr int B_ = 64, L_ = 80, E_ = 256, H_ = 256, C_ = 4, DT_ = 100;
constexpr int N_ = B_ * L_;          // 5120
constexpr int G4_ = 4 * H_;          // 1024
constexpr int DH2_ = 2 * H_;         // 512
constexpr int DF_ = 4 * L_ * H_;     // 81920
constexpr float EPS_ = 1e-5f;

// ---------------------------------------------------------------------------
// rel[i][j] = tanh(mean(transE1[i]) - mean(transE2[j]))
__global__ void k_rel(const float* __restrict__ tE1, const float* __restrict__ tE2,
                      float* __restrict__ rel) {
    __shared__ float m1[80], m2[80];
    int t = threadIdx.x;
    if (t < 80) {
        float s = 0.f;
        for (int k = 0; k < DT_; ++k) s += tE1[t * DT_ + k];
        m1[t] = s * (1.0f / DT_);
    } else if (t < 160) {
        int i = t - 80;
        float s = 0.f;
        for (int k = 0; k < DT_; ++k) s += tE2[i * DT_ + k];
        m2[i] = s * (1.0f / DT_);
    }
    __syncthreads();
    for (int idx = t; idx < 80 * 80; idx += blockDim.x)
        rel[idx] = tanhf(m1[idx / 80] - m2[idx % 80]);
}

// ---------------------------------------------------------------------------
// e[r][c] = table[argX[r]][c] ; rows 0..N-1 from arg1, N..2N-1 from arg2
__global__ void k_embed(const int* __restrict__ arg1, const int* __restrict__ arg2,
                        const float* __restrict__ table, float* __restrict__ e) {
    int r = blockIdx.x;                 // 0..2N-1
    int rr = (r >= N_) ? (r - N_) : r;
    int idx = (r >= N_) ? arg2[rr] : arg1[rr];
    e[(size_t)r * E_ + threadIdx.x] = table[(size_t)idx * E_ + threadIdx.x];
}

// ---------------------------------------------------------------------------
// Pack Wcat = [Wih_f; Wih_b] (2048x256), bcat = bih+bhh per dir, Rt = R^T
__global__ void k_pack(const float* __restrict__ Wih_f, const float* __restrict__ Wih_b,
                       const float* __restrict__ bih_f, const float* __restrict__ bhh_f,
                       const float* __restrict__ bih_b, const float* __restrict__ bhh_b,
                       const float* __restrict__ R,
                       float* __restrict__ Wcat, float* __restrict__ bcat,
                       float* __restrict__ Rt) {
    int i = blockIdx.x * blockDim.x + threadIdx.x;   // grid covers 524288
    if (i < 2 * G4_ * E_)
        Wcat[i] = (i < G4_ * E_) ? Wih_f[i] : Wih_b[i - G4_ * E_];
    if (i < 2 * G4_)
        bcat[i] = (i < G4_) ? (bih_f[i] + bhh_f[i]) : (bih_b[i - G4_] + bhh_b[i - G4_]);
    if (i < 512 * 512) {
        int m = i >> 9, k = i & 511;
        Rt[i] = R[k * 512 + m];
    }
}

// ---------------------------------------------------------------------------
// Generic f32 GEMM: C[M x Nn] = A[M x K] * Bt[Nn x K]^T (+ bias[Nn])
// 64x64 tile, BK=32, 256 threads, 4x4 micro-tile.
__global__ __launch_bounds__(256) void k_gemm(const float* __restrict__ A,
                                              const float* __restrict__ Bt,
                                              const float* __restrict__ bias,
                                              float* __restrict__ Cout,
                                              int M, int Nn, int K) {
    __shared__ float As[32][65];
    __shared__ float Bs[32][65];
    int tid = threadIdx.x;
    int tx = tid & 15, ty = tid >> 4;
    int r0 = blockIdx.y * 64, c0 = blockIdx.x * 64;
    float acc[4][4] = {};
    for (int kk = 0; kk < K; kk += 32) {
        #pragma unroll
        for (int t = 0; t < 8; ++t) {
            int idx = t * 256 + tid;
            int m = idx >> 5, k = idx & 31;
            As[k][m] = A[(size_t)(r0 + m) * K + kk + k];
            Bs[k][m] = Bt[(size_t)(c0 + m) * K + kk + k];
        }
        __syncthreads();
        #pragma unroll
        for (int k = 0; k < 32; ++k) {
            float a[4], b[4];
            #pragma unroll
            for (int i = 0; i < 4; ++i) a[i] = As[k][ty * 4 + i];
            #pragma unroll
            for (int j = 0; j < 4; ++j) b[j] = Bs[k][tx * 4 + j];
            #pragma unroll
            for (int i = 0; i < 4; ++i)
                #pragma unroll
                for (int j = 0; j < 4; ++j) acc[i][j] += a[i] * b[j];
        }
        __syncthreads();
    }
    #pragma unroll
    for (int i = 0; i < 4; ++i) {
        int r = r0 + ty * 4 + i;
        #pragma unroll
        for (int j = 0; j < 4; ++j) {
            int c = c0 + tx * 4 + j;
            float v = acc[i][j] + (bias ? bias[c] : 0.f);
            Cout[(size_t)r * Nn + c] = v;
        }
    }
}

// ---------------------------------------------------------------------------
// LSTM recurrence. 64 blocks: block = (dir d, 4 chains of that dir).
// Chain index cc in [0,128): w = cc>>6 (which input), b = cc&63.
// Thread j owns h-dim j for all 4 chains.
__global__ __launch_bounds__(256) void k_lstm(const float* __restrict__ xg,
                                              const float* __restrict__ Whh_f,
                                              const float* __restrict__ Whh_b,
                                              float* __restrict__ o1,
                                              float* __restrict__ o2) {
    int blk = blockIdx.x;          // 0..63
    int d = blk >> 5;              // 0 fwd, 1 bwd
    int grp = blk & 31;
    const float* __restrict__ W = d ? Whh_b : Whh_f;
    int j = threadIdx.x;

    __shared__ float hs[4][256];
    hs[0][j] = 0.f; hs[1][j] = 0.f; hs[2][j] = 0.f; hs[3][j] = 0.f;
    __syncthreads();

    float cst[4] = {0.f, 0.f, 0.f, 0.f};

    const float* __restrict__ Wi = W + (size_t)j * H_;
    const float* __restrict__ Wf = W + (size_t)(H_ + j) * H_;
    const float* __restrict__ Wg = W + (size_t)(2 * H_ + j) * H_;
    const float* __restrict__ Wo = W + (size_t)(3 * H_ + j) * H_;

    for (int t = 0; t < L_; ++t) {
        int l = d ? (L_ - 1 - t) : t;
        float gi[4] = {}, gf[4] = {}, gg[4] = {}, go[4] = {};
        #pragma unroll 2
        for (int k = 0; k < H_; k += 4) {
            float4 wi = *(const float4*)(Wi + k);
            float4 wf = *(const float4*)(Wf + k);
            float4 wg = *(const float4*)(Wg + k);
            float4 wo = *(const float4*)(Wo + k);
            #pragma unroll
            for (int q = 0; q < 4; ++q) {
                float4 hv = *(const float4*)(&hs[q][k]);
                gi[q] += wi.x * hv.x + wi.y * hv.y + wi.z * hv.z + wi.w * hv.w;
                gf[q] += wf.x * hv.x + wf.y * hv.y + wf.z * hv.z + wf.w * hv.w;
                gg[q] += wg.x * hv.x + wg.y * hv.y + wg.z * hv.z + wg.w * hv.w;
                go[q] += wo.x * hv.x + wo.y * hv.y + wo.z * hv.z + wo.w * hv.w;
            }
        }
        float hnew[4];
        #pragma unroll
        for (int q = 0; q < 4; ++q) {
            int cc = grp * 4 + q;
            int w = cc >> 6, b = cc & 63;
            const float* xr = xg + ((size_t)(w * N_ + b * L_ + l)) * (2 * G4_) + d * G4_;
            float vi = xr[j] + gi[q];
            float vf = xr[H_ + j] + gf[q];
            float vg = xr[2 * H_ + j] + gg[q];
            float vo = xr[3 * H_ + j] + go[q];
            float si = 1.f / (1.f + expf(-vi));
            float sf = 1.f / (1.f + expf(-vf));
            float so = 1.f / (1.f + expf(-vo));
            float tg = tanhf(vg);
            cst[q] = sf * cst[q] + si * tg;
            float hn = so * tanhf(cst[q]);
            hnew[q] = hn;
            float* o = w ? o2 : o1;
            o[((size_t)(b * L_ + l)) * DH2_ + d * H_ + j] = hn;
        }
        __syncthreads();
        #pragma unroll
        for (int q = 0; q < 4; ++q) hs[q][j] = hnew[q];
        __syncthreads();
    }
}

// ---------------------------------------------------------------------------
// Fused: last = tanh(u * t2^T) + kg ; E = exp(last); per-tile row/col sums.
__global__ __launch_bounds__(256) void k_big(const float* __restrict__ A,   // u (N x 512)
                                             const float* __restrict__ Bt,  // t2 (N x 512)
                                             const float* __restrict__ rel,
                                             float* __restrict__ Ebuf,
                                             float* __restrict__ rowpart,
                                             float* __restrict__ colpart) {
    __shared__ float As[32][65];
    __shared__ float Bs[32][65];
    __shared__ float rowred[64][17];
    __shared__ float colred[64][17];
    int tid = threadIdx.x;
    int tx = tid & 15, ty = tid >> 4;
    int r0 = blockIdx.y * 64, c0 = blockIdx.x * 64;
    float acc[4][4] = {};
    for (int kk = 0; kk < DH2_; kk += 32) {
        #pragma unroll
        for (int t = 0; t < 8; ++t) {
            int idx = t * 256 + tid;
            int m = idx >> 5, k = idx & 31;
            As[k][m] = A[(size_t)(r0 + m) * DH2_ + kk + k];
            Bs[k][m] = Bt[(size_t)(c0 + m) * DH2_ + kk + k];
        }
        __syncthreads();
        #pragma unroll
        for (int k = 0; k < 32; ++k) {
            float a[4], b[4];
            #pragma unroll
            for (int i = 0; i < 4; ++i) a[i] = As[k][ty * 4 + i];
            #pragma unroll
            for (int j = 0; j < 4; ++j) b[j] = Bs[k][tx * 4 + j];
            #pragma unroll
            for (int i = 0; i < 4; ++i)
                #pragma unroll
                for (int j = 0; j < 4; ++j) acc[i][j] += a[i] * b[j];
        }
        __syncthreads();
    }
    float rsum[4] = {0.f, 0.f, 0.f, 0.f};
    float csum[4] = {0.f, 0.f, 0.f, 0.f};
    #pragma unroll
    for (int i = 0; i < 4; ++i) {
        int r = r0 + ty * 4 + i;
        int bi = r / 80, li = r - bi * 80;
        #pragma unroll
        for (int j = 0; j < 4; ++j) {
            int c = c0 + tx * 4 + j;
            int bj = c / 80, lj = c - bj * 80;
            float v = tanhf(acc[i][j]);
            if (bi == bj) v += rel[li * 80 + lj];
            float e = expf(v);
            Ebuf[(size_t)r * N_ + c] = e;
            rsum[i] += e;
            csum[j] += e;
        }
    }
    #pragma unroll
    for (int i = 0; i < 4; ++i) rowred[ty * 4 + i][tx] = rsum[i];
    #pragma unroll
    for (int j = 0; j < 4; ++j) colred[tx * 4 + j][ty] = csum[j];
    __syncthreads();
    if (tid < 64) {
        float s = 0.f;
        #pragma unroll
        for (int t = 0; t < 16; ++t) s += rowred[tid][t];
        rowpart[(size_t)blockIdx.x * N_ + r0 + tid] = s;
    } else if (tid < 128) {
        int n = tid - 64;
        float s = 0.f;
        #pragma unroll
        for (int t = 0; t < 16; ++t) s += colred[n][t];
        colpart[(size_t)blockIdx.y * N_ + c0 + n] = s;
    }
}

// ---------------------------------------------------------------------------
__global__ void k_redsum(const float* __restrict__ rowpart, const float* __restrict__ colpart,
                         float* __restrict__ rowinv, float* __restrict__ colinv) {
    int i = blockIdx.x * blockDim.x + threadIdx.x;
    if (i < N_) {
        float rs = 0.f, cs = 0.f;
        for (int t = 0; t < 80; ++t) {
            rs += rowpart[(size_t)t * N_ + i];
            cs += colpart[(size_t)t * N_ + i];
        }
        rowinv[i] = 1.f / rs;
        colinv[i] = 1.f / cs;
    }
}

// sf2[i] = (1/N) * sum_j E[i][j] * colinv[j]
__global__ __launch_bounds__(256) void k_sf2(const float* __restrict__ Ebuf,
                                             const float* __restrict__ colinv,
                                             float* __restrict__ sf2) {
    int i = blockIdx.x;
    float p = 0.f;
    for (int j = threadIdx.x; j < N_; j += 256)
        p += Ebuf[(size_t)i * N_ + j] * colinv[j];
    __shared__ float red[256];
    red[threadIdx.x] = p;
    __syncthreads();
    for (int s = 128; s > 0; s >>= 1) {
        if (threadIdx.x < s) red[threadIdx.x] += red[threadIdx.x + s];
        __syncthreads();
    }
    if (threadIdx.x == 0) sf2[i] = red[0] * (1.f / N_);
}

// sf1part[ti][j] = sum_{i in tile ti} E[i][j] * rowinv[i]
__global__ __launch_bounds__(256) void k_sf1part(const float* __restrict__ Ebuf,
                                                 const float* __restrict__ rowinv,
                                                 float* __restrict__ sf1part) {
    int ti = blockIdx.x;
    int i0 = ti * 64;
    float acc[20] = {};
    for (int ii = 0; ii < 64; ++ii) {
        float inv = rowinv[i0 + ii];
        const float* row = Ebuf + (size_t)(i0 + ii) * N_;
        #pragma unroll
        for (int q = 0; q < 20; ++q) acc[q] += row[threadIdx.x + q * 256] * inv;
    }
    #pragma unroll
    for (int q = 0; q < 20; ++q)
        sf1part[(size_t)ti * N_ + threadIdx.x + q * 256] = acc[q];
}

__global__ void k_sf1red(const float* __restrict__ sf1part, float* __restrict__ sf1) {
    int j = blockIdx.x * blockDim.x + threadIdx.x;
    if (j < N_) {
        float s = 0.f;
        for (int t = 0; t < 80; ++t) s += sf1part[(size_t)t * N_ + j];
        sf1[j] = s * (1.f / N_);
    }
}

// ---------------------------------------------------------------------------
// BatchNorm stats per feature f (two-pass, biased variance).
__global__ void k_bnstats(const float* __restrict__ o1, const float* __restrict__ o2,
                          const float* __restrict__ sf1, const float* __restrict__ sf2,
                          float* __restrict__ bnmu, float* __restrict__ bnrstd) {
    int f = blockIdx.x * 256 + threadIdx.x;     // < 81920
    int seg = f / (L_ * DH2_);
    int rem = f - seg * (L_ * DH2_);
    int l = rem >> 9, hh = rem & 511;
    const float* t = seg ? o2 : o1;
    const float* sf = seg ? sf1 : sf2;
    float s = 0.f;
    for (int b = 0; b < B_; ++b) {
        int row = b * L_ + l;
        s += t[(size_t)row * DH2_ + hh] * sf[row];
    }
    float mu = s * (1.f / B_);
    float v = 0.f;
    for (int b = 0; b < B_; ++b) {
        int row = b * L_ + l;
        float x = t[(size_t)row * DH2_ + hh] * sf[row] - mu;
        v += x * x;
    }
    v *= (1.f / B_);
    bnmu[f] = mu;
    bnrstd[f] = rsqrtf(v + EPS_);
}

// logits + log_softmax, one block per batch element
__global__ __launch_bounds__(256) void k_logits(const float* __restrict__ o1,
                                                const float* __restrict__ o2,
                                                const float* __restrict__ sf1,
                                                const float* __restrict__ sf2,
                                                const float* __restrict__ bnmu,
                                                const float* __restrict__ bnrstd,
                                                const float* __restrict__ gamma,
                                                const float* __restrict__ beta,
                                                const float* __restrict__ fcW,
                                                const float* __restrict__ fcb,
                                                float* __restrict__ dout) {
    int b = blockIdx.x;
    int tid = threadIdx.x;
    float acc[4] = {0.f, 0.f, 0.f, 0.f};
    for (int f = tid; f < DF_; f += 256) {
        int seg = f / (L_ * DH2_);
        int rem = f - seg * (L_ * DH2_);
        int l = rem >> 9, hh = rem & 511;
        int row = b * L_ + l;
        float val = (seg ? o2 : o1)[(size_t)row * DH2_ + hh] * (seg ? sf1 : sf2)[row];
        float xn = (val - bnmu[f]) * bnrstd[f] * gamma[f] + beta[f];
        #pragma unroll
        for (int c = 0; c < 4; ++c) acc[c] += xn * fcW[(size_t)c * DF_ + f];
    }
    __shared__ float red[4][257];
    #pragma unroll
    for (int c = 0; c < 4; ++c) red[c][tid] = acc[c];
    __syncthreads();
    for (int s = 128; s > 0; s >>= 1) {
        if (tid < s)
            #pragma unroll
            for (int c = 0; c < 4; ++c) red[c][tid] += red[c][tid + s];
        __syncthreads();
    }
    if (tid == 0) {
        float lg[4], mx = -1e30f;
        #pragma unroll
        for (int c = 0; c < 4; ++c) { lg[c] = red[c][0] + fcb[c]; mx = fmaxf(mx, lg[c]); }
        float se = 0.f;
        #pragma unroll
        for (int c = 0; c < 4; ++c) se += expf(lg[c] - mx);
        float lse = mx + logf(se);
        #pragma unroll
        for (int c = 0; c < 4; ++c) dout[b * 4 + c] = lg[c] - lse;
    }
}

// ---------------------------------------------------------------------------
extern "C" void kernel_launch(void* const* d_in, const int* in_sizes, int n_in,
                              void* d_out, int out_size, void* d_ws, size_t ws_size,
                              hipStream_t stream) {
    const int* arg1 = (const int*)d_in[0];
    const int* arg2 = (const int*)d_in[1];
    const float* tE1 = (const float*)d_in[3];
    const float* tE2 = (const float*)d_in[4];
    const float* table = (const float*)d_in[5];
    const float* Wih_f = (const float*)d_in[6];
    const float* Whh_f = (const float*)d_in[7];
    const float* bih_f = (const float*)d_in[8];
    const float* bhh_f = (const float*)d_in[9];
    const float* Wih_b = (const float*)d_in[10];
    const float* Whh_b = (const float*)d_in[11];
    const float* bih_b = (const float*)d_in[12];
    const float* bhh_b = (const float*)d_in[13];
    const float* R = (const float*)d_in[14];
    const float* gamma = (const float*)d_in[15];
    const float* beta = (const float*)d_in[16];
    const float* fcW = (const float*)d_in[17];
    const float* fcb = (const float*)d_in[18];
    float* dout = (float*)d_out;

    float* ws = (float*)d_ws;
    size_t off = 0;
    auto alloc = [&](size_t n) { float* p = ws + off; off += n; return p; };

    float* rel = alloc(80 * 80);
    float* e = alloc((size_t)2 * N_ * E_);          // X for xg GEMM (e1 then e2)
    float* Wcat = alloc((size_t)2 * G4_ * E_);
    float* bcat = alloc(2 * G4_);
    float* Rt = alloc(512 * 512);
    float* o1 = alloc((size_t)N_ * DH2_);
    float* o2 = alloc((size_t)N_ * DH2_);
    float* u = alloc((size_t)N_ * DH2_);
    float* rowpart = alloc((size_t)80 * N_);
    float* colpart = alloc((size_t)80 * N_);
    float* rowinv = alloc(N_);
    float* colinv = alloc(N_);
    float* sf1part = alloc((size_t)80 * N_);
    float* sf1 = alloc(N_);
    float* sf2 = alloc(N_);
    float* bnmu = alloc(DF_);
    float* bnrstd = alloc(DF_);
    // xg (10240 x 2048 = 21.0M floats) and Ebuf (5120 x 5120 = 26.2M floats)
    // have disjoint lifetimes -> alias one region of the larger size.
    float* xg = alloc((size_t)N_ * N_);
    float* Ebuf = xg;

    // 1) rel matrix
    k_rel<<<1, 256, 0, stream>>>(tE1, tE2, rel);
    // 2) embedding gather (e1, e2 stacked)
    k_embed<<<2 * N_, 256, 0, stream>>>(arg1, arg2, table, e);
    // 3) pack Wcat/bcat/Rt
    k_pack<<<2048, 256, 0, stream>>>(Wih_f, Wih_b, bih_f, bhh_f, bih_b, bhh_b, R,
                                     Wcat, bcat, Rt);
    // 4) xg = e @ Wcat^T + bcat   (10240 x 2048, K=256)
    k_gemm<<<dim3(2 * G4_ / 64, 2 * N_ / 64), 256, 0, stream>>>(
        e, Wcat, bcat, xg, 2 * N_, 2 * G4_, E_);
    // 5) LSTM recurrence -> o1, o2
    k_lstm<<<64, 256, 0, stream>>>(xg, Whh_f, Whh_b, o1, o2);
    // 6) u = t1 @ R  (via Rt)
    k_gemm<<<dim3(DH2_ / 64, N_ / 64), 256, 0, stream>>>(
        o1, Rt, nullptr, u, N_, DH2_, DH2_);
    // 7) E = exp(tanh(u t2^T) + kg), tile row/col partial sums
    k_big<<<dim3(N_ / 64, N_ / 64), 256, 0, stream>>>(u, o2, rel, Ebuf, rowpart, colpart);
    // 8) row/col sums -> inverses
    k_redsum<<<(N_ + 255) / 256, 256, 0, stream>>>(rowpart, colpart, rowinv, colinv);
    // 9) sf2[i] = (1/N) sum_j E/colsum
    k_sf2<<<N_, 256, 0, stream>>>(Ebuf, colinv, sf2);
    // 10) sf1 partials + reduce
    k_sf1part<<<80, 256, 0, stream>>>(Ebuf, rowinv, sf1part);
    k_sf1red<<<(N_ + 255) / 256, 256, 0, stream>>>(sf1part, sf1);
    // 11) BN stats
    k_bnstats<<<DF_ / 256, 256, 0, stream>>>(o1, o2, sf1, sf2, bnmu, bnrstd);
    // 12) FC + log_softmax
    k_logits<<<B_, 256, 0, stream>>>(o1, o2, sf1, sf2, bnmu, bnrstd, gamma, beta,
                                     fcW, fcb, dout);
}

// Round 2
// 3060.317 us; speedup vs baseline: 1.3403x; 1.3403x over previous
//
#include <hip/hip_runtime.h>
#include <cstddef>
#include <cstdint>

typedef unsigned short ushort_t;

// Problem constants (match reference)
constexpr int B_ = 64, L_ = 80, E_ = 256, H_ = 256, C_ = 4, DT_ = 100;
constexpr int N_ = B_ * L_;          // 5120
constexpr int G4_ = 4 * H_;          // 1024
constexpr int DH2_ = 2 * H_;         // 512
constexpr int DF_ = 4 * L_ * H_;     // 81920
constexpr float EPS_ = 1e-5f;

typedef short s8v __attribute__((ext_vector_type(8)));
typedef float f4v __attribute__((ext_vector_type(4)));

__device__ inline ushort_t f2bf_rn(float x) {
    uint32_t u = __builtin_bit_cast(uint32_t, x);
    uint32_t r = (u + 0x7fffu + ((u >> 16) & 1u)) >> 16;
    return (ushort_t)r;
}
__device__ inline float bf2f(ushort_t h) {
    uint32_t u = ((uint32_t)h) << 16;
    return __builtin_bit_cast(float, u);
}

// ---------------------------------------------------------------------------
// rel[i][j] = tanh(mean(transE1[i]) - mean(transE2[j]))
__global__ void k_rel(const float* __restrict__ tE1, const float* __restrict__ tE2,
                      float* __restrict__ rel) {
    __shared__ float m1[80], m2[80];
    int t = threadIdx.x;
    if (t < 80) {
        float s = 0.f;
        for (int k = 0; k < DT_; ++k) s += tE1[t * DT_ + k];
        m1[t] = s * (1.0f / DT_);
    } else if (t < 160) {
        int i = t - 80;
        float s = 0.f;
        for (int k = 0; k < DT_; ++k) s += tE2[i * DT_ + k];
        m2[i] = s * (1.0f / DT_);
    }
    __syncthreads();
    for (int idx = t; idx < 80 * 80; idx += blockDim.x)
        rel[idx] = tanhf(m1[idx / 80] - m2[idx % 80]);
}

// ---------------------------------------------------------------------------
// e[r][c] = table[argX[r]][c] ; rows 0..N-1 from arg1, N..2N-1 from arg2
__global__ void k_embed(const int* __restrict__ arg1, const int* __restrict__ arg2,
                        const float* __restrict__ table, float* __restrict__ e) {
    int r = blockIdx.x;                 // 0..2N-1
    int rr = (r >= N_) ? (r - N_) : r;
    int idx = (r >= N_) ? arg2[rr] : arg1[rr];
    e[(size_t)r * E_ + threadIdx.x] = table[(size_t)idx * E_ + threadIdx.x];
}

// ---------------------------------------------------------------------------
// Pack Wcat = [Wih_f; Wih_b] (2048x256), bcat = bih+bhh per dir, Rt = R^T
__global__ void k_pack(const float* __restrict__ Wih_f, const float* __restrict__ Wih_b,
                       const float* __restrict__ bih_f, const float* __restrict__ bhh_f,
                       const float* __restrict__ bih_b, const float* __restrict__ bhh_b,
                       const float* __restrict__ R,
                       float* __restrict__ Wcat, float* __restrict__ bcat,
                       float* __restrict__ Rt) {
    int i = blockIdx.x * blockDim.x + threadIdx.x;   // grid covers 524288
    if (i < 2 * G4_ * E_)
        Wcat[i] = (i < G4_ * E_) ? Wih_f[i] : Wih_b[i - G4_ * E_];
    if (i < 2 * G4_)
        bcat[i] = (i < G4_) ? (bih_f[i] + bhh_f[i]) : (bih_b[i - G4_] + bhh_b[i - G4_]);
    if (i < 512 * 512) {
        int m = i >> 9, k = i & 511;
        Rt[i] = R[k * 512 + m];
    }
}

// ---------------------------------------------------------------------------
// Pack Whh (per dir) into MFMA B-fragment order, split bf16 hi/lo.
// Layout idx = ((((d*16 + w)*8 + kt)*4 + g)*64 + lane)*8 + e
// B[k][col] where col = g*256 + w*16 + (lane&15), k = kt*32 + (lane>>4)*8 + e
__global__ void k_packw(const float* __restrict__ Whh_f, const float* __restrict__ Whh_b,
                        ushort_t* __restrict__ Bhi, ushort_t* __restrict__ Blo) {
    int idx = blockIdx.x * 256 + threadIdx.x;      // total 524288
    if (idx >= 2 * 16 * 8 * 4 * 64 * 8) return;
    int e = idx & 7;
    int lane = (idx >> 3) & 63;
    int g = (idx >> 9) & 3;
    int kt = (idx >> 11) & 7;
    int w = (idx >> 14) & 15;
    int d = idx >> 18;
    int c = lane & 15, q = lane >> 4;
    int row = g * 256 + w * 16 + c;                 // Whh row (gate-major, pytorch i,f,g,o)
    int k = kt * 32 + q * 8 + e;                    // Whh col (h dim)
    const float* W = d ? Whh_b : Whh_f;
    float v = W[row * 256 + k];
    ushort_t hi = f2bf_rn(v);
    Bhi[idx] = hi;
    Blo[idx] = f2bf_rn(v - bf2f(hi));
}

// ---------------------------------------------------------------------------
// Generic f32 GEMM: C[M x Nn] = A[M x K] * Bt[Nn x K]^T (+ bias[Nn])
__global__ __launch_bounds__(256) void k_gemm(const float* __restrict__ A,
                                              const float* __restrict__ Bt,
                                              const float* __restrict__ bias,
                                              float* __restrict__ Cout,
                                              int M, int Nn, int K) {
    __shared__ float As[32][65];
    __shared__ float Bs[32][65];
    int tid = threadIdx.x;
    int tx = tid & 15, ty = tid >> 4;
    int r0 = blockIdx.y * 64, c0 = blockIdx.x * 64;
    float acc[4][4] = {};
    for (int kk = 0; kk < K; kk += 32) {
        #pragma unroll
        for (int t = 0; t < 8; ++t) {
            int idx = t * 256 + tid;
            int m = idx >> 5, k = idx & 31;
            As[k][m] = A[(size_t)(r0 + m) * K + kk + k];
            Bs[k][m] = Bt[(size_t)(c0 + m) * K + kk + k];
        }
        __syncthreads();
        #pragma unroll
        for (int k = 0; k < 32; ++k) {
            float a[4], b[4];
            #pragma unroll
            for (int i = 0; i < 4; ++i) a[i] = As[k][ty * 4 + i];
            #pragma unroll
            for (int j = 0; j < 4; ++j) b[j] = Bs[k][tx * 4 + j];
            #pragma unroll
            for (int i = 0; i < 4; ++i)
                #pragma unroll
                for (int j = 0; j < 4; ++j) acc[i][j] += a[i] * b[j];
        }
        __syncthreads();
    }
    #pragma unroll
    for (int i = 0; i < 4; ++i) {
        int r = r0 + ty * 4 + i;
        #pragma unroll
        for (int j = 0; j < 4; ++j) {
            int c = c0 + tx * 4 + j;
            float v = acc[i][j] + (bias ? bias[c] : 0.f);
            Cout[(size_t)r * Nn + c] = v;
        }
    }
}

// ---------------------------------------------------------------------------
// MFMA LSTM recurrence. 16 blocks x 1024 threads.
// block: d = blk>>3 (dir), grp = blk&7 -> chains [grp*16, grp*16+16) of this dir.
// chain cc in [0,128): w = cc>>6 (which input), bb = cc&63 (batch).
// wave w_id owns jh slice [w_id*16, w_id*16+16).
// Per step: gates(16x1024) = h(16x256) @ WhhT via split-bf16 MFMA (hi+lo).
__global__ __launch_bounds__(1024) void k_lstm2(
        const float* __restrict__ xg,
        const ushort_t* __restrict__ Bhi, const ushort_t* __restrict__ Blo,
        float* __restrict__ o1, float* __restrict__ o2) {
    int blk = blockIdx.x;
    int d = blk >> 3, grp = blk & 7;
    int tid = threadIdx.x;
    int w_id = tid >> 6;
    int lane = tid & 63;
    int c16 = lane & 15, q = lane >> 4;

    __shared__ ushort_t Ahi[16][280];    // [chain][k=h-dim], stride 280 (560B, 16B-aligned)
    __shared__ ushort_t Alo[16][280];

    for (int i = tid; i < 16 * 280; i += 1024) {
        (&Ahi[0][0])[i] = 0;
        (&Alo[0][0])[i] = 0;
    }
    __syncthreads();

    // this lane's 4 output chains (rows q*4+r of the 16-chain tile)
    int xrow[4], orow[4];
    float* optr[4];
    #pragma unroll
    for (int r = 0; r < 4; ++r) {
        int cc = grp * 16 + q * 4 + r;
        int w = cc >> 6, bb = cc & 63;
        xrow[r] = w * N_ + bb * L_;
        orow[r] = bb * L_;
        optr[r] = w ? o2 : o1;
    }
    int jh = w_id * 16 + c16;

    float cst[4] = {0.f, 0.f, 0.f, 0.f};

    const s8v* BH = (const s8v*)Bhi;
    const s8v* BL = (const s8v*)Blo;
    int sbase = (d * 16 + w_id) * 8;     // * (4*64) applied below

    for (int t = 0; t < L_; ++t) {
        int l = d ? (L_ - 1 - t) : t;

        // xg gate biases for this lane's 4 chains x 4 gates
        float xv[4][4];
        #pragma unroll
        for (int r = 0; r < 4; ++r) {
            const float* xp = xg + (size_t)(xrow[r] + l) * 2048 + d * 1024 + jh;
            #pragma unroll
            for (int g = 0; g < 4; ++g) xv[r][g] = xp[g * 256];
        }

        f4v acc[4] = {};
        #pragma unroll
        for (int kt = 0; kt < 8; ++kt) {
            s8v ahi = *(const s8v*)&Ahi[c16][kt * 32 + q * 8];
            s8v alo = *(const s8v*)&Alo[c16][kt * 32 + q * 8];
            #pragma unroll
            for (int g = 0; g < 4; ++g) {
                int sidx = ((sbase + kt) * 4 + g) * 64 + lane;
                s8v bhi = BH[sidx];
                s8v blo = BL[sidx];
                acc[g] = __builtin_amdgcn_mfma_f32_16x16x32_bf16(ahi, bhi, acc[g], 0, 0, 0);
                acc[g] = __builtin_amdgcn_mfma_f32_16x16x32_bf16(ahi, blo, acc[g], 0, 0, 0);
                acc[g] = __builtin_amdgcn_mfma_f32_16x16x32_bf16(alo, bhi, acc[g], 0, 0, 0);
            }
        }

        // gate math: C/D row = q*4+r (chain), col = c16 (jh)
        float hn[4];
        #pragma unroll
        for (int r = 0; r < 4; ++r) {
            float pi = acc[0][r] + xv[r][0];
            float pf = acc[1][r] + xv[r][1];
            float pg = acc[2][r] + xv[r][2];
            float po = acc[3][r] + xv[r][3];
            float si = 1.f / (1.f + expf(-pi));
            float sf = 1.f / (1.f + expf(-pf));
            float so = 1.f / (1.f + expf(-po));
            float tg = tanhf(pg);
            cst[r] = sf * cst[r] + si * tg;
            float h = so * tanhf(cst[r]);
            hn[r] = h;
            optr[r][(size_t)(orow[r] + l) * DH2_ + d * H_ + jh] = h;
        }

        __syncthreads();     // all waves done reading A for this step
        #pragma unroll
        for (int r = 0; r < 4; ++r) {
            ushort_t hi = f2bf_rn(hn[r]);
            Ahi[q * 4 + r][jh] = hi;
            Alo[q * 4 + r][jh] = f2bf_rn(hn[r] - bf2f(hi));
        }
        __syncthreads();     // new h visible
    }
}

// ---------------------------------------------------------------------------
// Fused: last = tanh(u * t2^T) + kg ; E = exp(last); per-tile row/col sums.
__global__ __launch_bounds__(256) void k_big(const float* __restrict__ A,   // u (N x 512)
                                             const float* __restrict__ Bt,  // t2 (N x 512)
                                             const float* __restrict__ rel,
                                             float* __restrict__ Ebuf,
                                             float* __restrict__ rowpart,
                                             float* __restrict__ colpart) {
    __shared__ float As[32][65];
    __shared__ float Bs[32][65];
    __shared__ float rowred[64][17];
    __shared__ float colred[64][17];
    int tid = threadIdx.x;
    int tx = tid & 15, ty = tid >> 4;
    int r0 = blockIdx.y * 64, c0 = blockIdx.x * 64;
    float acc[4][4] = {};
    for (int kk = 0; kk < DH2_; kk += 32) {
        #pragma unroll
        for (int t = 0; t < 8; ++t) {
            int idx = t * 256 + tid;
            int m = idx >> 5, k = idx & 31;
            As[k][m] = A[(size_t)(r0 + m) * DH2_ + kk + k];
            Bs[k][m] = Bt[(size_t)(c0 + m) * DH2_ + kk + k];
        }
        __syncthreads();
        #pragma unroll
        for (int k = 0; k < 32; ++k) {
            float a[4], b[4];
            #pragma unroll
            for (int i = 0; i < 4; ++i) a[i] = As[k][ty * 4 + i];
            #pragma unroll
            for (int j = 0; j < 4; ++j) b[j] = Bs[k][tx * 4 + j];
            #pragma unroll
            for (int i = 0; i < 4; ++i)
                #pragma unroll
                for (int j = 0; j < 4; ++j) acc[i][j] += a[i] * b[j];
        }
        __syncthreads();
    }
    float rsum[4] = {0.f, 0.f, 0.f, 0.f};
    float csum[4] = {0.f, 0.f, 0.f, 0.f};
    #pragma unroll
    for (int i = 0; i < 4; ++i) {
        int r = r0 + ty * 4 + i;
        int bi = r / 80, li = r - bi * 80;
        #pragma unroll
        for (int j = 0; j < 4; ++j) {
            int c = c0 + tx * 4 + j;
            int bj = c / 80, lj = c - bj * 80;
            float v = tanhf(acc[i][j]);
            if (bi == bj) v += rel[li * 80 + lj];
            float e = expf(v);
            Ebuf[(size_t)r * N_ + c] = e;
            rsum[i] += e;
            csum[j] += e;
        }
    }
    #pragma unroll
    for (int i = 0; i < 4; ++i) rowred[ty * 4 + i][tx] = rsum[i];
    #pragma unroll
    for (int j = 0; j < 4; ++j) colred[tx * 4 + j][ty] = csum[j];
    __syncthreads();
    if (tid < 64) {
        float s = 0.f;
        #pragma unroll
        for (int t = 0; t < 16; ++t) s += rowred[tid][t];
        rowpart[(size_t)blockIdx.x * N_ + r0 + tid] = s;
    } else if (tid < 128) {
        int n = tid - 64;
        float s = 0.f;
        #pragma unroll
        for (int t = 0; t < 16; ++t) s += colred[n][t];
        colpart[(size_t)blockIdx.y * N_ + c0 + n] = s;
    }
}

// ---------------------------------------------------------------------------
__global__ void k_redsum(const float* __restrict__ rowpart, const float* __restrict__ colpart,
                         float* __restrict__ rowinv, float* __restrict__ colinv) {
    int i = blockIdx.x * blockDim.x + threadIdx.x;
    if (i < N_) {
        float rs = 0.f, cs = 0.f;
        for (int t = 0; t < 80; ++t) {
            rs += rowpart[(size_t)t * N_ + i];
            cs += colpart[(size_t)t * N_ + i];
        }
        rowinv[i] = 1.f / rs;
        colinv[i] = 1.f / cs;
    }
}

// sf2[i] = (1/N) * sum_j E[i][j] * colinv[j]
__global__ __launch_bounds__(256) void k_sf2(const float* __restrict__ Ebuf,
                                             const float* __restrict__ colinv,
                                             float* __restrict__ sf2) {
    int i = blockIdx.x;
    float p = 0.f;
    for (int j = threadIdx.x; j < N_; j += 256)
        p += Ebuf[(size_t)i * N_ + j] * colinv[j];
    __shared__ float red[256];
    red[threadIdx.x] = p;
    __syncthreads();
    for (int s = 128; s > 0; s >>= 1) {
        if (threadIdx.x < s) red[threadIdx.x] += red[threadIdx.x + s];
        __syncthreads();
    }
    if (threadIdx.x == 0) sf2[i] = red[0] * (1.f / N_);
}

// sf1part[ti][j] = sum_{i in tile ti} E[i][j] * rowinv[i]
__global__ __launch_bounds__(256) void k_sf1part(const float* __restrict__ Ebuf,
                                                 const float* __restrict__ rowinv,
                                                 float* __restrict__ sf1part) {
    int ti = blockIdx.x;
    int i0 = ti * 64;
    float acc[20] = {};
    for (int ii = 0; ii < 64; ++ii) {
        float inv = rowinv[i0 + ii];
        const float* row = Ebuf + (size_t)(i0 + ii) * N_;
        #pragma unroll
        for (int q = 0; q < 20; ++q) acc[q] += row[threadIdx.x + q * 256] * inv;
    }
    #pragma unroll
    for (int q = 0; q < 20; ++q)
        sf1part[(size_t)ti * N_ + threadIdx.x + q * 256] = acc[q];
}

__global__ void k_sf1red(const float* __restrict__ sf1part, float* __restrict__ sf1) {
    int j = blockIdx.x * blockDim.x + threadIdx.x;
    if (j < N_) {
        float s = 0.f;
        for (int t = 0; t < 80; ++t) s += sf1part[(size_t)t * N_ + j];
        sf1[j] = s * (1.f / N_);
    }
}

// ---------------------------------------------------------------------------
// BatchNorm stats per feature f (two-pass, biased variance).
__global__ void k_bnstats(const float* __restrict__ o1, const float* __restrict__ o2,
                          const float* __restrict__ sf1, const float* __restrict__ sf2,
                          float* __restrict__ bnmu, float* __restrict__ bnrstd) {
    int f = blockIdx.x * 256 + threadIdx.x;     // < 81920
    int seg = f / (L_ * DH2_);
    int rem = f - seg * (L_ * DH2_);
    int l = rem >> 9, hh = rem & 511;
    const float* t = seg ? o2 : o1;
    const float* sf = seg ? sf1 : sf2;
    float s = 0.f;
    for (int b = 0; b < B_; ++b) {
        int row = b * L_ + l;
        s += t[(size_t)row * DH2_ + hh] * sf[row];
    }
    float mu = s * (1.f / B_);
    float v = 0.f;
    for (int b = 0; b < B_; ++b) {
        int row = b * L_ + l;
        float x = t[(size_t)row * DH2_ + hh] * sf[row] - mu;
        v += x * x;
    }
    v *= (1.f / B_);
    bnmu[f] = mu;
    bnrstd[f] = rsqrtf(v + EPS_);
}

// logits + log_softmax, one block per batch element
__global__ __launch_bounds__(256) void k_logits(const float* __restrict__ o1,
                                                const float* __restrict__ o2,
                                                const float* __restrict__ sf1,
                                                const float* __restrict__ sf2,
                                                const float* __restrict__ bnmu,
                                                const float* __restrict__ bnrstd,
                                                const float* __restrict__ gamma,
                                                const float* __restrict__ beta,
                                                const float* __restrict__ fcW,
                                                const float* __restrict__ fcb,
                                                float* __restrict__ dout) {
    int b = blockIdx.x;
    int tid = threadIdx.x;
    float acc[4] = {0.f, 0.f, 0.f, 0.f};
    for (int f = tid; f < DF_; f += 256) {
        int seg = f / (L_ * DH2_);
        int rem = f - seg * (L_ * DH2_);
        int l = rem >> 9, hh = rem & 511;
        int row = b * L_ + l;
        float val = (seg ? o2 : o1)[(size_t)row * DH2_ + hh] * (seg ? sf1 : sf2)[row];
        float xn = (val - bnmu[f]) * bnrstd[f] * gamma[f] + beta[f];
        #pragma unroll
        for (int c = 0; c < 4; ++c) acc[c] += xn * fcW[(size_t)c * DF_ + f];
    }
    __shared__ float red[4][257];
    #pragma unroll
    for (int c = 0; c < 4; ++c) red[c][tid] = acc[c];
    __syncthreads();
    for (int s = 128; s > 0; s >>= 1) {
        if (tid < s)
            #pragma unroll
            for (int c = 0; c < 4; ++c) red[c][tid] += red[c][tid + s];
        __syncthreads();
    }
    if (tid == 0) {
        float lg[4], mx = -1e30f;
        #pragma unroll
        for (int c = 0; c < 4; ++c) { lg[c] = red[c][0] + fcb[c]; mx = fmaxf(mx, lg[c]); }
        float se = 0.f;
        #pragma unroll
        for (int c = 0; c < 4; ++c) se += expf(lg[c] - mx);
        float lse = mx + logf(se);
        #pragma unroll
        for (int c = 0; c < 4; ++c) dout[b * 4 + c] = lg[c] - lse;
    }
}

// ---------------------------------------------------------------------------
extern "C" void kernel_launch(void* const* d_in, const int* in_sizes, int n_in,
                              void* d_out, int out_size, void* d_ws, size_t ws_size,
                              hipStream_t stream) {
    const int* arg1 = (const int*)d_in[0];
    const int* arg2 = (const int*)d_in[1];
    const float* tE1 = (const float*)d_in[3];
    const float* tE2 = (const float*)d_in[4];
    const float* table = (const float*)d_in[5];
    const float* Wih_f = (const float*)d_in[6];
    const float* Whh_f = (const float*)d_in[7];
    const float* bih_f = (const float*)d_in[8];
    const float* bhh_f = (const float*)d_in[9];
    const float* Wih_b = (const float*)d_in[10];
    const float* Whh_b = (const float*)d_in[11];
    const float* bih_b = (const float*)d_in[12];
    const float* bhh_b = (const float*)d_in[13];
    const float* R = (const float*)d_in[14];
    const float* gamma = (const float*)d_in[15];
    const float* beta = (const float*)d_in[16];
    const float* fcW = (const float*)d_in[17];
    const float* fcb = (const float*)d_in[18];
    float* dout = (float*)d_out;

    float* ws = (float*)d_ws;
    size_t off = 0;
    auto alloc = [&](size_t n) { float* p = ws + off; off += n; return p; };

    float* rel = alloc(80 * 80);
    float* e = alloc((size_t)2 * N_ * E_);
    float* Wcat = alloc((size_t)2 * G4_ * E_);
    float* bcat = alloc(2 * G4_);
    float* Rt = alloc(512 * 512);
    float* o1 = alloc((size_t)N_ * DH2_);
    float* o2 = alloc((size_t)N_ * DH2_);
    float* u = alloc((size_t)N_ * DH2_);
    float* rowpart = alloc((size_t)80 * N_);
    float* colpart = alloc((size_t)80 * N_);
    float* rowinv = alloc(N_);
    float* colinv = alloc(N_);
    float* sf1part = alloc((size_t)80 * N_);
    float* sf1 = alloc(N_);
    float* sf2 = alloc(N_);
    float* bnmu = alloc(DF_);
    float* bnrstd = alloc(DF_);
    ushort_t* Bhi = (ushort_t*)alloc(262144);   // 524288 ushorts
    ushort_t* Blo = (ushort_t*)alloc(262144);
    // xg (21.0M floats) and Ebuf (26.2M floats): disjoint lifetimes -> alias.
    float* xg = alloc((size_t)N_ * N_);
    float* Ebuf = xg;

    // 1) rel matrix
    k_rel<<<1, 256, 0, stream>>>(tE1, tE2, rel);
    // 2) embedding gather
    k_embed<<<2 * N_, 256, 0, stream>>>(arg1, arg2, table, e);
    // 3) pack Wcat/bcat/Rt, and Whh -> MFMA B-fragments (split bf16)
    k_pack<<<2048, 256, 0, stream>>>(Wih_f, Wih_b, bih_f, bhh_f, bih_b, bhh_b, R,
                                     Wcat, bcat, Rt);
    k_packw<<<2048, 256, 0, stream>>>(Whh_f, Whh_b, Bhi, Blo);
    // 4) xg = e @ Wcat^T + bcat
    k_gemm<<<dim3(2 * G4_ / 64, 2 * N_ / 64), 256, 0, stream>>>(
        e, Wcat, bcat, xg, 2 * N_, 2 * G4_, E_);
    // 5) LSTM recurrence (MFMA, split-bf16) -> o1, o2
    k_lstm2<<<16, 1024, 0, stream>>>(xg, Bhi, Blo, o1, o2);
    // 6) u = t1 @ R
    k_gemm<<<dim3(DH2_ / 64, N_ / 64), 256, 0, stream>>>(
        o1, Rt, nullptr, u, N_, DH2_, DH2_);
    // 7) E = exp(tanh(u t2^T) + kg), tile row/col partial sums
    k_big<<<dim3(N_ / 64, N_ / 64), 256, 0, stream>>>(u, o2, rel, Ebuf, rowpart, colpart);
    // 8) row/col sums -> inverses
    k_redsum<<<(N_ + 255) / 256, 256, 0, stream>>>(rowpart, colpart, rowinv, colinv);
    // 9) sf2
    k_sf2<<<N_, 256, 0, stream>>>(Ebuf, colinv, sf2);
    // 10) sf1
    k_sf1part<<<80, 256, 0, stream>>>(Ebuf, rowinv, sf1part);
    k_sf1red<<<(N_ + 255) / 256, 256, 0, stream>>>(sf1part, sf1);
    // 11) BN stats
    k_bnstats<<<DF_ / 256, 256, 0, stream>>>(o1, o2, sf1, sf2, bnmu, bnrstd);
    // 12) FC + log_softmax
    k_logits<<<B_, 256, 0, stream>>>(o1, o2, sf1, sf2, bnmu, bnrstd, gamma, beta,
                                     fcW, fcb, dout);
}

// Round 3
// 3055.647 us; speedup vs baseline: 1.3424x; 1.0015x over previous
//
#include <hip/hip_runtime.h>
#include <cstddef>
#include <cstdint>

typedef unsigned short ushort_t;

constexpr int B_ = 64, L_ = 80, E_ = 256, H_ = 256, C_ = 4, DT_ = 100;
constexpr int N_ = B_ * L_;          // 5120
constexpr int G4_ = 4 * H_;          // 1024
constexpr int DH2_ = 2 * H_;         // 512
constexpr int DF_ = 4 * L_ * H_;     // 81920
constexpr float EPS_ = 1e-5f;

typedef short s8v __attribute__((ext_vector_type(8)));
typedef float f4v __attribute__((ext_vector_type(4)));

__device__ inline ushort_t f2bf_rn(float x) {
    uint32_t u = __builtin_bit_cast(uint32_t, x);
    uint32_t r = (u + 0x7fffu + ((u >> 16) & 1u)) >> 16;
    return (ushort_t)r;
}
__device__ inline float bf2f(ushort_t h) {
    uint32_t u = ((uint32_t)h) << 16;
    return __builtin_bit_cast(float, u);
}
__device__ inline float rcpf(float x) { return __builtin_amdgcn_rcpf(x); }
__device__ inline float sigm(float x) { return rcpf(1.f + __expf(-x)); }
__device__ inline float tanh_fast(float x) {
    float e2 = __expf(2.f * x);
    return 1.f - 2.f * rcpf(1.f + e2);
}

// ---------------------------------------------------------------------------
__global__ void k_rel(const float* __restrict__ tE1, const float* __restrict__ tE2,
                      float* __restrict__ rel) {
    __shared__ float m1[80], m2[80];
    int t = threadIdx.x;
    if (t < 80) {
        float s = 0.f;
        for (int k = 0; k < DT_; ++k) s += tE1[t * DT_ + k];
        m1[t] = s * (1.0f / DT_);
    } else if (t < 160) {
        int i = t - 80;
        float s = 0.f;
        for (int k = 0; k < DT_; ++k) s += tE2[i * DT_ + k];
        m2[i] = s * (1.0f / DT_);
    }
    __syncthreads();
    for (int idx = t; idx < 80 * 80; idx += blockDim.x)
        rel[idx] = tanhf(m1[idx / 80] - m2[idx % 80]);
}

// ---------------------------------------------------------------------------
__global__ void k_embed(const int* __restrict__ arg1, const int* __restrict__ arg2,
                        const float* __restrict__ table, float* __restrict__ e) {
    int r = blockIdx.x;                 // 0..2N-1
    int rr = (r >= N_) ? (r - N_) : r;
    int idx = (r >= N_) ? arg2[rr] : arg1[rr];
    e[(size_t)r * E_ + threadIdx.x] = table[(size_t)idx * E_ + threadIdx.x];
}

// ---------------------------------------------------------------------------
__global__ void k_pack(const float* __restrict__ Wih_f, const float* __restrict__ Wih_b,
                       const float* __restrict__ bih_f, const float* __restrict__ bhh_f,
                       const float* __restrict__ bih_b, const float* __restrict__ bhh_b,
                       const float* __restrict__ R,
                       float* __restrict__ Wcat, float* __restrict__ bcat,
                       float* __restrict__ Rt) {
    int i = blockIdx.x * blockDim.x + threadIdx.x;
    if (i < 2 * G4_ * E_)
        Wcat[i] = (i < G4_ * E_) ? Wih_f[i] : Wih_b[i - G4_ * E_];
    if (i < 2 * G4_)
        bcat[i] = (i < G4_) ? (bih_f[i] + bhh_f[i]) : (bih_b[i - G4_] + bhh_b[i - G4_]);
    if (i < 512 * 512) {
        int m = i >> 9, k = i & 511;
        Rt[i] = R[k * 512 + m];
    }
}

// ---------------------------------------------------------------------------
// Pack Whh into MFMA B-fragment order, split bf16 hi/lo.
// byte offset = (d*16+w)*32768 + kt*4096 + g*1024 + lane*16 + e*2
__global__ void k_packw(const float* __restrict__ Whh_f, const float* __restrict__ Whh_b,
                        ushort_t* __restrict__ Bhi, ushort_t* __restrict__ Blo) {
    int idx = blockIdx.x * 256 + threadIdx.x;      // total 524288
    if (idx >= 2 * 16 * 8 * 4 * 64 * 8) return;
    int e = idx & 7;
    int lane = (idx >> 3) & 63;
    int g = (idx >> 9) & 3;
    int kt = (idx >> 11) & 7;
    int w = (idx >> 14) & 15;
    int d = idx >> 18;
    int c = lane & 15, q = lane >> 4;
    int row = g * 256 + w * 16 + c;
    int k = kt * 32 + q * 8 + e;
    const float* W = d ? Whh_b : Whh_f;
    float v = W[row * 256 + k];
    ushort_t hi = f2bf_rn(v);
    Bhi[idx] = hi;
    Blo[idx] = f2bf_rn(v - bf2f(hi));
}

// ---------------------------------------------------------------------------
__global__ __launch_bounds__(256) void k_gemm(const float* __restrict__ A,
                                              const float* __restrict__ Bt,
                                              const float* __restrict__ bias,
                                              float* __restrict__ Cout,
                                              int M, int Nn, int K) {
    __shared__ float As[32][65];
    __shared__ float Bs[32][65];
    int tid = threadIdx.x;
    int tx = tid & 15, ty = tid >> 4;
    int r0 = blockIdx.y * 64, c0 = blockIdx.x * 64;
    float acc[4][4] = {};
    for (int kk = 0; kk < K; kk += 32) {
        #pragma unroll
        for (int t = 0; t < 8; ++t) {
            int idx = t * 256 + tid;
            int m = idx >> 5, k = idx & 31;
            As[k][m] = A[(size_t)(r0 + m) * K + kk + k];
            Bs[k][m] = Bt[(size_t)(c0 + m) * K + kk + k];
        }
        __syncthreads();
        #pragma unroll
        for (int k = 0; k < 32; ++k) {
            float a[4], b[4];
            #pragma unroll
            for (int i = 0; i < 4; ++i) a[i] = As[k][ty * 4 + i];
            #pragma unroll
            for (int j = 0; j < 4; ++j) b[j] = Bs[k][tx * 4 + j];
            #pragma unroll
            for (int i = 0; i < 4; ++i)
                #pragma unroll
                for (int j = 0; j < 4; ++j) acc[i][j] += a[i] * b[j];
        }
        __syncthreads();
    }
    #pragma unroll
    for (int i = 0; i < 4; ++i) {
        int r = r0 + ty * 4 + i;
        #pragma unroll
        for (int j = 0; j < 4; ++j) {
            int c = c0 + tx * 4 + j;
            float v = acc[i][j] + (bias ? bias[c] : 0.f);
            Cout[(size_t)r * Nn + c] = v;
        }
    }
}

// ---------------------------------------------------------------------------
// MFMA LSTM recurrence, v3. 16 blocks x 512 threads (8 waves).
#define MFMA_B16(a, b, c) __builtin_amdgcn_mfma_f32_16x16x32_bf16((a), (b), (c), 0, 0, 0)

__global__ __launch_bounds__(512, 2) void k_lstm3(
        const float* __restrict__ xg,
        const ushort_t* __restrict__ Bhi, const ushort_t* __restrict__ Blo,
        float* __restrict__ o1) {
    int blk = blockIdx.x;
    int d = blk >> 3, grp = blk & 7;
    int tid = threadIdx.x;
    int w_id = tid >> 6;
    int lane = tid & 63;
    int c16 = lane & 15, q = lane >> 4;

    __shared__ ushort_t Abuf[2][2][16][264];   // [buf][hi/lo][chain][k], 33.8 KB
    for (int i = tid; i < 2 * 2 * 16 * 264; i += 512) (&Abuf[0][0][0][0])[i] = 0;
    __syncthreads();

    uint32_t xbase[4];   // xg byte offsets
    uint32_t obase[4];   // o element offsets
    int l0 = d ? (L_ - 1) : 0;
    #pragma unroll
    for (int r = 0; r < 4; ++r) {
        int cc = grp * 16 + q * 4 + r;
        int w = cc >> 6, bb = cc & 63;
        xbase[r] = (uint32_t)((w * N_ + bb * L_ + l0) * 2048 + d * 1024
                              + (2 * w_id) * 16 + c16) * 4u;
        obase[r] = (uint32_t)(w * N_ * DH2_ + (bb * L_ + l0) * DH2_ + d * H_
                              + (2 * w_id) * 16 + c16);
    }
    const int xstep = d ? -8192 : 8192;
    const int ostep = d ? -DH2_ : DH2_;

    const char* __restrict__ BHc = (const char*)Bhi;
    const char* __restrict__ BLc = (const char*)Blo;
    const char* __restrict__ XGc = (const char*)xg;
    uint32_t vb0 = (uint32_t)(d * 16 + 2 * w_id + 0) * 32768u + (uint32_t)lane * 16u;
    uint32_t vb1 = (uint32_t)(d * 16 + 2 * w_id + 1) * 32768u + (uint32_t)lane * 16u;

    float cst0[4] = {0.f, 0.f, 0.f, 0.f};
    float cst1[4] = {0.f, 0.f, 0.f, 0.f};

    s8v bh0a[4], bl0a[4], bh1a[4], bl1a[4];
    s8v bh0b[4], bl0b[4], bh1b[4], bl1b[4];
    f4v acc0[4], acc1[4];
    float xv0[4][4], xv1[4][4];

#define LDB(kt, H0v, L0v, H1v, L1v)                                        \
    {   uint32_t off0 = vb0 + (uint32_t)(kt) * 4096u;                      \
        uint32_t off1 = vb1 + (uint32_t)(kt) * 4096u;                      \
        _Pragma("unroll")                                                  \
        for (int g = 0; g < 4; ++g) {                                      \
            H0v[g] = *(const s8v*)(BHc + (size_t)(off0 + g * 1024));       \
            L0v[g] = *(const s8v*)(BLc + (size_t)(off0 + g * 1024));       \
            H1v[g] = *(const s8v*)(BHc + (size_t)(off1 + g * 1024));       \
            L1v[g] = *(const s8v*)(BLc + (size_t)(off1 + g * 1024));       \
        } }

#define STEPKT(kt, H0v, L0v, H1v, L1v, PRE)                                \
    {   s8v ahi = *(const s8v*)&Abuf[pb][0][c16][(kt) * 32 + q * 8];       \
        s8v alo = *(const s8v*)&Abuf[pb][1][c16][(kt) * 32 + q * 8];       \
        _Pragma("unroll")                                                  \
        for (int g = 0; g < 4; ++g) {                                      \
            acc0[g] = MFMA_B16(ahi, H0v[g], acc0[g]);                      \
            acc0[g] = MFMA_B16(ahi, L0v[g], acc0[g]);                      \
            acc0[g] = MFMA_B16(alo, H0v[g], acc0[g]);                      \
            acc1[g] = MFMA_B16(ahi, H1v[g], acc1[g]);                      \
            acc1[g] = MFMA_B16(ahi, L1v[g], acc1[g]);                      \
            acc1[g] = MFMA_B16(alo, H1v[g], acc1[g]);                      \
        }                                                                  \
        PRE; }

#define GATES(ACC, XV, CST, SOFF)                                          \
        _Pragma("unroll")                                                  \
        for (int r = 0; r < 4; ++r) {                                      \
            float pi = ACC[0][r] + XV[r][0];                               \
            float pf = ACC[1][r] + XV[r][1];                               \
            float pg = ACC[2][r] + XV[r][2];                               \
            float po = ACC[3][r] + XV[r][3];                               \
            float si = sigm(pi), sf_ = sigm(pf), so = sigm(po);            \
            float tg = tanh_fast(pg);                                      \
            CST[r] = sf_ * CST[r] + si * tg;                               \
            float h = so * tanh_fast(CST[r]);                              \
            o1[(size_t)(obase[r] + (SOFF))] = h;                           \
            ushort_t hh = f2bf_rn(h);                                      \
            int jw = (2 * w_id) * 16 + c16 + (SOFF);                       \
            Abuf[pb ^ 1][0][q * 4 + r][jw] = hh;                           \
            Abuf[pb ^ 1][1][q * 4 + r][jw] = f2bf_rn(h - bf2f(hh));        \
        }

    int pb = 0;
    for (int t = 0; t < L_; ++t) {
        LDB(0, bh0a, bl0a, bh1a, bl1a);
        LDB(1, bh0b, bl0b, bh1b, bl1b);

        #pragma unroll
        for (int r = 0; r < 4; ++r) {
            const char* xp = XGc + (size_t)xbase[r];
            #pragma unroll
            for (int g = 0; g < 4; ++g) {
                xv0[r][g] = *(const float*)(xp + g * 1024);
                xv1[r][g] = *(const float*)(xp + g * 1024 + 64);
            }
        }

        #pragma unroll
        for (int g = 0; g < 4; ++g) {
            acc0[g] = (f4v){0.f, 0.f, 0.f, 0.f};
            acc1[g] = (f4v){0.f, 0.f, 0.f, 0.f};
        }

        STEPKT(0, bh0a, bl0a, bh1a, bl1a, LDB(2, bh0a, bl0a, bh1a, bl1a));
        STEPKT(1, bh0b, bl0b, bh1b, bl1b, LDB(3, bh0b, bl0b, bh1b, bl1b));
        STEPKT(2, bh0a, bl0a, bh1a, bl1a, LDB(4, bh0a, bl0a, bh1a, bl1a));
        STEPKT(3, bh0b, bl0b, bh1b, bl1b, LDB(5, bh0b, bl0b, bh1b, bl1b));
        STEPKT(4, bh0a, bl0a, bh1a, bl1a, LDB(6, bh0a, bl0a, bh1a, bl1a));
        STEPKT(5, bh0b, bl0b, bh1b, bl1b, LDB(7, bh0b, bl0b, bh1b, bl1b));
        STEPKT(6, bh0a, bl0a, bh1a, bl1a, );
        STEPKT(7, bh0b, bl0b, bh1b, bl1b, );

        GATES(acc0, xv0, cst0, 0);
        GATES(acc1, xv1, cst1, 16);

        __syncthreads();
        pb ^= 1;
        #pragma unroll
        for (int r = 0; r < 4; ++r) {
            xbase[r] += (uint32_t)xstep;
            obase[r] += (uint32_t)ostep;
        }
    }
#undef LDB
#undef STEPKT
#undef GATES
}

// ---------------------------------------------------------------------------
__global__ __launch_bounds__(256) void k_big(const float* __restrict__ A,
                                             const float* __restrict__ Bt,
                                             const float* __restrict__ rel,
                                             float* __restrict__ Ebuf,
                                             float* __restrict__ rowpart,
                                             float* __restrict__ colpart) {
    __shared__ float As[32][65];
    __shared__ float Bs[32][65];
    __shared__ float rowred[64][17];
    __shared__ float colred[64][17];
    int tid = threadIdx.x;
    int tx = tid & 15, ty = tid >> 4;
    int r0 = blockIdx.y * 64, c0 = blockIdx.x * 64;
    float acc[4][4] = {};
    for (int kk = 0; kk < DH2_; kk += 32) {
        #pragma unroll
        for (int t = 0; t < 8; ++t) {
            int idx = t * 256 + tid;
            int m = idx >> 5, k = idx & 31;
            As[k][m] = A[(size_t)(r0 + m) * DH2_ + kk + k];
            Bs[k][m] = Bt[(size_t)(c0 + m) * DH2_ + kk + k];
        }
        __syncthreads();
        #pragma unroll
        for (int k = 0; k < 32; ++k) {
            float a[4], b[4];
            #pragma unroll
            for (int i = 0; i < 4; ++i) a[i] = As[k][ty * 4 + i];
            #pragma unroll
            for (int j = 0; j < 4; ++j) b[j] = Bs[k][tx * 4 + j];
            #pragma unroll
            for (int i = 0; i < 4; ++i)
                #pragma unroll
                for (int j = 0; j < 4; ++j) acc[i][j] += a[i] * b[j];
        }
        __syncthreads();
    }
    float rsum[4] = {0.f, 0.f, 0.f, 0.f};
    float csum[4] = {0.f, 0.f, 0.f, 0.f};
    #pragma unroll
    for (int i = 0; i < 4; ++i) {
        int r = r0 + ty * 4 + i;
        int bi = r / 80, li = r - bi * 80;
        #pragma unroll
        for (int j = 0; j < 4; ++j) {
            int c = c0 + tx * 4 + j;
            int bj = c / 80, lj = c - bj * 80;
            float v = tanhf(acc[i][j]);
            if (bi == bj) v += rel[li * 80 + lj];
            float e = expf(v);
            Ebuf[(size_t)r * N_ + c] = e;
            rsum[i] += e;
            csum[j] += e;
        }
    }
    #pragma unroll
    for (int i = 0; i < 4; ++i) rowred[ty * 4 + i][tx] = rsum[i];
    #pragma unroll
    for (int j = 0; j < 4; ++j) colred[tx * 4 + j][ty] = csum[j];
    __syncthreads();
    if (tid < 64) {
        float s = 0.f;
        #pragma unroll
        for (int t = 0; t < 16; ++t) s += rowred[tid][t];
        rowpart[(size_t)blockIdx.x * N_ + r0 + tid] = s;
    } else if (tid < 128) {
        int n = tid - 64;
        float s = 0.f;
        #pragma unroll
        for (int t = 0; t < 16; ++t) s += colred[n][t];
        colpart[(size_t)blockIdx.y * N_ + c0 + n] = s;
    }
}

// ---------------------------------------------------------------------------
__global__ void k_redsum(const float* __restrict__ rowpart, const float* __restrict__ colpart,
                         float* __restrict__ rowinv, float* __restrict__ colinv) {
    int i = blockIdx.x * blockDim.x + threadIdx.x;
    if (i < N_) {
        float rs = 0.f, cs = 0.f;
        for (int t = 0; t < 80; ++t) {
            rs += rowpart[(size_t)t * N_ + i];
            cs += colpart[(size_t)t * N_ + i];
        }
        rowinv[i] = 1.f / rs;
        colinv[i] = 1.f / cs;
    }
}

__global__ __launch_bounds__(256) void k_sf2(const float* __restrict__ Ebuf,
                                             const float* __restrict__ colinv,
                                             float* __restrict__ sf2) {
    int i = blockIdx.x;
    float p = 0.f;
    for (int j = threadIdx.x; j < N_; j += 256)
        p += Ebuf[(size_t)i * N_ + j] * colinv[j];
    __shared__ float red[256];
    red[threadIdx.x] = p;
    __syncthreads();
    for (int s = 128; s > 0; s >>= 1) {
        if (threadIdx.x < s) red[threadIdx.x] += red[threadIdx.x + s];
        __syncthreads();
    }
    if (threadIdx.x == 0) sf2[i] = red[0] * (1.f / N_);
}

__global__ __launch_bounds__(256) void k_sf1part(const float* __restrict__ Ebuf,
                                                 const float* __restrict__ rowinv,
                                                 float* __restrict__ sf1part) {
    int ti = blockIdx.x;
    int i0 = ti * 64;
    float acc[20] = {};
    for (int ii = 0; ii < 64; ++ii) {
        float inv = rowinv[i0 + ii];
        const float* row = Ebuf + (size_t)(i0 + ii) * N_;
        #pragma unroll
        for (int q = 0; q < 20; ++q) acc[q] += row[threadIdx.x + q * 256] * inv;
    }
    #pragma unroll
    for (int q = 0; q < 20; ++q)
        sf1part[(size_t)ti * N_ + threadIdx.x + q * 256] = acc[q];
}

__global__ void k_sf1red(const float* __restrict__ sf1part, float* __restrict__ sf1) {
    int j = blockIdx.x * blockDim.x + threadIdx.x;
    if (j < N_) {
        float s = 0.f;
        for (int t = 0; t < 80; ++t) s += sf1part[(size_t)t * N_ + j];
        sf1[j] = s * (1.f / N_);
    }
}

// ---------------------------------------------------------------------------
__global__ void k_bnstats(const float* __restrict__ o1, const float* __restrict__ o2,
                          const float* __restrict__ sf1, const float* __restrict__ sf2,
                          float* __restrict__ bnmu, float* __restrict__ bnrstd) {
    int f = blockIdx.x * 256 + threadIdx.x;
    int seg = f / (L_ * DH2_);
    int rem = f - seg * (L_ * DH2_);
    int l = rem >> 9, hh = rem & 511;
    const float* t = seg ? o2 : o1;
    const float* sf = seg ? sf1 : sf2;
    float s = 0.f;
    for (int b = 0; b < B_; ++b) {
        int row = b * L_ + l;
        s += t[(size_t)row * DH2_ + hh] * sf[row];
    }
    float mu = s * (1.f / B_);
    float v = 0.f;
    for (int b = 0; b < B_; ++b) {
        int row = b * L_ + l;
        float x = t[(size_t)row * DH2_ + hh] * sf[row] - mu;
        v += x * x;
    }
    v *= (1.f / B_);
    bnmu[f] = mu;
    bnrstd[f] = rsqrtf(v + EPS_);
}

__global__ __launch_bounds__(256) void k_logits(const float* __restrict__ o1,
                                                const float* __restrict__ o2,
                                                const float* __restrict__ sf1,
                                                const float* __restrict__ sf2,
                                                const float* __restrict__ bnmu,
                                                const float* __restrict__ bnrstd,
                                                const float* __restrict__ gamma,
                                                const float* __restrict__ beta,
                                                const float* __restrict__ fcW,
                                                const float* __restrict__ fcb,
                                                float* __restrict__ dout) {
    int b = blockIdx.x;
    int tid = threadIdx.x;
    float acc[4] = {0.f, 0.f, 0.f, 0.f};
    for (int f = tid; f < DF_; f += 256) {
        int seg = f / (L_ * DH2_);
        int rem = f - seg * (L_ * DH2_);
        int l = rem >> 9, hh = rem & 511;
        int row = b * L_ + l;
        float val = (seg ? o2 : o1)[(size_t)row * DH2_ + hh] * (seg ? sf1 : sf2)[row];
        float xn = (val - bnmu[f]) * bnrstd[f] * gamma[f] + beta[f];
        #pragma unroll
        for (int c = 0; c < 4; ++c) acc[c] += xn * fcW[(size_t)c * DF_ + f];
    }
    __shared__ float red[4][257];
    #pragma unroll
    for (int c = 0; c < 4; ++c) red[c][tid] = acc[c];
    __syncthreads();
    for (int s = 128; s > 0; s >>= 1) {
        if (tid < s)
            #pragma unroll
            for (int c = 0; c < 4; ++c) red[c][tid] += red[c][tid + s];
        __syncthreads();
    }
    if (tid == 0) {
        float lg[4], mx = -1e30f;
        #pragma unroll
        for (int c = 0; c < 4; ++c) { lg[c] = red[c][0] + fcb[c]; mx = fmaxf(mx, lg[c]); }
        float se = 0.f;
        #pragma unroll
        for (int c = 0; c < 4; ++c) se += expf(lg[c] - mx);
        float lse = mx + logf(se);
        #pragma unroll
        for (int c = 0; c < 4; ++c) dout[b * 4 + c] = lg[c] - lse;
    }
}

// ---------------------------------------------------------------------------
extern "C" void kernel_launch(void* const* d_in, const int* in_sizes, int n_in,
                              void* d_out, int out_size, void* d_ws, size_t ws_size,
                              hipStream_t stream) {
    const int* arg1 = (const int*)d_in[0];
    const int* arg2 = (const int*)d_in[1];
    const float* tE1 = (const float*)d_in[3];
    const float* tE2 = (const float*)d_in[4];
    const float* table = (const float*)d_in[5];
    const float* Wih_f = (const float*)d_in[6];
    const float* Whh_f = (const float*)d_in[7];
    const float* bih_f = (const float*)d_in[8];
    const float* bhh_f = (const float*)d_in[9];
    const float* Wih_b = (const float*)d_in[10];
    const float* Whh_b = (const float*)d_in[11];
    const float* bih_b = (const float*)d_in[12];
    const float* bhh_b = (const float*)d_in[13];
    const float* R = (const float*)d_in[14];
    const float* gamma = (const float*)d_in[15];
    const float* beta = (const float*)d_in[16];
    const float* fcW = (const float*)d_in[17];
    const float* fcb = (const float*)d_in[18];
    float* dout = (float*)d_out;

    float* ws = (float*)d_ws;
    size_t off = 0;
    auto alloc = [&](size_t n) { float* p = ws + off; off += n; return p; };

    float* rel = alloc(80 * 80);
    float* e = alloc((size_t)2 * N_ * E_);
    float* Wcat = alloc((size_t)2 * G4_ * E_);
    float* bcat = alloc(2 * G4_);
    float* Rt = alloc(512 * 512);
    float* o1 = alloc((size_t)N_ * DH2_);    // o2 MUST follow o1 contiguously
    float* o2 = alloc((size_t)N_ * DH2_);    // (k_lstm3 writes o2 via o1 + N*512)
    float* u = alloc((size_t)N_ * DH2_);
    float* rowpart = alloc((size_t)80 * N_);
    float* colpart = alloc((size_t)80 * N_);
    float* rowinv = alloc(N_);
    float* colinv = alloc(N_);
    float* sf1part = alloc((size_t)80 * N_);
    float* sf1 = alloc(N_);
    float* sf2 = alloc(N_);
    float* bnmu = alloc(DF_);
    float* bnrstd = alloc(DF_);
    ushort_t* Bhi = (ushort_t*)alloc(262144);
    ushort_t* Blo = (ushort_t*)alloc(262144);
    float* xg = alloc((size_t)N_ * N_);   // aliased with Ebuf
    float* Ebuf = xg;

    k_rel<<<1, 256, 0, stream>>>(tE1, tE2, rel);
    k_embed<<<2 * N_, 256, 0, stream>>>(arg1, arg2, table, e);
    k_pack<<<2048, 256, 0, stream>>>(Wih_f, Wih_b, bih_f, bhh_f, bih_b, bhh_b, R,
                                     Wcat, bcat, Rt);
    k_packw<<<2048, 256, 0, stream>>>(Whh_f, Whh_b, Bhi, Blo);
    k_gemm<<<dim3(2 * G4_ / 64, 2 * N_ / 64), 256, 0, stream>>>(
        e, Wcat, bcat, xg, 2 * N_, 2 * G4_, E_);
    k_lstm3<<<16, 512, 0, stream>>>(xg, Bhi, Blo, o1);
    k_gemm<<<dim3(DH2_ / 64, N_ / 64), 256, 0, stream>>>(
        o1, Rt, nullptr, u, N_, DH2_, DH2_);
    k_big<<<dim3(N_ / 64, N_ / 64), 256, 0, stream>>>(u, o2, rel, Ebuf, rowpart, colpart);
    k_redsum<<<(N_ + 255) / 256, 256, 0, stream>>>(rowpart, colpart, rowinv, colinv);
    k_sf2<<<N_, 256, 0, stream>>>(Ebuf, colinv, sf2);
    k_sf1part<<<80, 256, 0, stream>>>(Ebuf, rowinv, sf1part);
    k_sf1red<<<(N_ + 255) / 256, 256, 0, stream>>>(sf1part, sf1);
    k_bnstats<<<DF_ / 256, 256, 0, stream>>>(o1, o2, sf1, sf2, bnmu, bnrstd);
    k_logits<<<B_, 256, 0, stream>>>(o1, o2, sf1, sf2, bnmu, bnrstd, gamma, beta,
                                     fcW, fcb, dout);
}

// Round 4
// 1497.131 us; speedup vs baseline: 2.7397x; 2.0410x over previous
//
#include <hip/hip_runtime.h>
#include <cstddef>
#include <cstdint>

typedef unsigned short ushort_t;

constexpr int B_ = 64, L_ = 80, E_ = 256, H_ = 256, C_ = 4, DT_ = 100;
constexpr int N_ = B_ * L_;          // 5120
constexpr int G4_ = 4 * H_;          // 1024
constexpr int DH2_ = 2 * H_;         // 512
constexpr int DF_ = 4 * L_ * H_;     // 81920
constexpr float EPS_ = 1e-5f;
constexpr int FB_USH = 32768;        // ushorts per (d,par,Mh) fragment buffer (64 KB)

typedef short s8v __attribute__((ext_vector_type(8)));
typedef float f4v __attribute__((ext_vector_type(4)));

__device__ inline ushort_t f2bf_rn(float x) {
    uint32_t u = __builtin_bit_cast(uint32_t, x);
    uint32_t r = (u + 0x7fffu + ((u >> 16) & 1u)) >> 16;
    return (ushort_t)r;
}
__device__ inline float bf2f(ushort_t h) {
    uint32_t u = ((uint32_t)h) << 16;
    return __builtin_bit_cast(float, u);
}
__device__ inline float rcpf(float x) { return __builtin_amdgcn_rcpf(x); }
__device__ inline float sigm(float x) { return rcpf(1.f + __expf(-x)); }
__device__ inline float tanh_fast(float x) {
    float e2 = __expf(2.f * x);
    return 1.f - 2.f * rcpf(1.f + e2);
}

// ---------------------------------------------------------------------------
__global__ void k_rel(const float* __restrict__ tE1, const float* __restrict__ tE2,
                      float* __restrict__ rel) {
    __shared__ float m1[80], m2[80];
    int t = threadIdx.x;
    if (t < 80) {
        float s = 0.f;
        for (int k = 0; k < DT_; ++k) s += tE1[t * DT_ + k];
        m1[t] = s * (1.0f / DT_);
    } else if (t < 160) {
        int i = t - 80;
        float s = 0.f;
        for (int k = 0; k < DT_; ++k) s += tE2[i * DT_ + k];
        m2[i] = s * (1.0f / DT_);
    }
    __syncthreads();
    for (int idx = t; idx < 80 * 80; idx += blockDim.x)
        rel[idx] = tanhf(m1[idx / 80] - m2[idx % 80]);
}

// ---------------------------------------------------------------------------
__global__ void k_embed(const int* __restrict__ arg1, const int* __restrict__ arg2,
                        const float* __restrict__ table, float* __restrict__ e) {
    int r = blockIdx.x;                 // 0..2N-1
    int rr = (r >= N_) ? (r - N_) : r;
    int idx = (r >= N_) ? arg2[rr] : arg1[rr];
    e[(size_t)r * E_ + threadIdx.x] = table[(size_t)idx * E_ + threadIdx.x];
}

// ---------------------------------------------------------------------------
__global__ void k_pack(const float* __restrict__ Wih_f, const float* __restrict__ Wih_b,
                       const float* __restrict__ bih_f, const float* __restrict__ bhh_f,
                       const float* __restrict__ bih_b, const float* __restrict__ bhh_b,
                       const float* __restrict__ R,
                       float* __restrict__ Wcat, float* __restrict__ bcat,
                       float* __restrict__ Rt) {
    int i = blockIdx.x * blockDim.x + threadIdx.x;
    if (i < 2 * G4_ * E_)
        Wcat[i] = (i < G4_ * E_) ? Wih_f[i] : Wih_b[i - G4_ * E_];
    if (i < 2 * G4_)
        bcat[i] = (i < G4_) ? (bih_f[i] + bhh_f[i]) : (bih_b[i - G4_] + bhh_b[i - G4_]);
    if (i < 512 * 512) {
        int m = i >> 9, k = i & 511;
        Rt[i] = R[k * 512 + m];
    }
}

// ---------------------------------------------------------------------------
// Pack Whh into MFMA B-fragment order, split bf16 hi/lo.
// ushort index = (((d*16 + s)*8 + kt)*4 + g)*64*8 + lane*8 + e
// maps to W[g*256 + s*16 + (lane&15)][kt*32 + (lane>>4)*8 + e]
__global__ void k_packw(const float* __restrict__ Whh_f, const float* __restrict__ Whh_b,
                        ushort_t* __restrict__ Bhi, ushort_t* __restrict__ Blo) {
    int idx = blockIdx.x * 256 + threadIdx.x;      // total 524288
    if (idx >= 2 * 16 * 8 * 4 * 64 * 8) return;
    int e = idx & 7;
    int lane = (idx >> 3) & 63;
    int g = (idx >> 9) & 3;
    int kt = (idx >> 11) & 7;
    int w = (idx >> 14) & 15;
    int d = idx >> 18;
    int c = lane & 15, q = lane >> 4;
    int row = g * 256 + w * 16 + c;
    int k = kt * 32 + q * 8 + e;
    const float* W = d ? Whh_b : Whh_f;
    float v = W[row * 256 + k];
    ushort_t hi = f2bf_rn(v);
    Bhi[idx] = hi;
    Blo[idx] = f2bf_rn(v - bf2f(hi));
}

// ---------------------------------------------------------------------------
// Zero flags + fragment double-buffers each launch (graph-replay safe).
__global__ void k_initlstm(ushort_t* __restrict__ fragbuf, int* __restrict__ flags) {
    int i = blockIdx.x * 256 + threadIdx.x;
    if (i < 64) flags[i] = 0;
    uint4* p = (uint4*)fragbuf;          // 512 KB total = 32768 uint4
    for (int jj = i; jj < 32768; jj += gridDim.x * 256)
        p[jj] = make_uint4(0u, 0u, 0u, 0u);
}

// ---------------------------------------------------------------------------
// Persistent flag-dataflow LSTM. 64 blocks x 1024 threads, 1 block/CU.
// block bid = (d*2 + Mh)*16 + s :
//   d = direction, Mh = chain-half (0: input1 batch 0..63, 1: input2),
//   s = jh-slice [s*16, s*16+16).
// Wave w_id = (gate g = w_id&3, mt = w_id>>2): computes gate g preacts for
// chains [mt*16, mt*16+16) x jh slice s. W fragments live in 64 VGPRs.
// h exchanged via global fragbuf[d][par][Mh] in A-fragment order (hi/lo
// planes), guarded by per-group device-scope flags.
#define MFMA_B16(a, b, c) __builtin_amdgcn_mfma_f32_16x16x32_bf16((a), (b), (c), 0, 0, 0)

__global__ __launch_bounds__(1024, 4) void k_lstm4(
        const float* __restrict__ xg,
        const ushort_t* __restrict__ Bhi, const ushort_t* __restrict__ Blo,
        float* __restrict__ o1, float* __restrict__ o2,
        ushort_t* __restrict__ fragbuf, int* __restrict__ flags) {
    const int bid = blockIdx.x;
    const int s = bid & 15;
    const int Mh = (bid >> 4) & 1;
    const int d = bid >> 5;
    const int tid = threadIdx.x;
    const int w_id = tid >> 6, lane = tid & 63;
    const int g = w_id & 3, mt = w_id >> 2;
    const int c16 = lane & 15, qq = lane >> 4;

    __shared__ uint32_t smem4[16384];            // 64 KB
    ushort_t* Ahi = (ushort_t*)smem4;            // [mt4][kt8][lane64][e8]
    ushort_t* Alo = Ahi + 16384;                 // +32 KB
    float* pre = (float*)smem4;                  // [g4][c64][j16] (aliases Ahi)

    // resident B fragments: gate g, slice s, all 8 kt (hi+lo) = 64 VGPRs
    s8v bh[8], bl[8];
    {
        const s8v* BH = (const s8v*)Bhi;
        const s8v* BL = (const s8v*)Blo;
        int base = (d * 16 + s) * 2048 + g * 64 + lane;
        #pragma unroll
        for (int kt = 0; kt < 8; ++kt) {
            bh[kt] = BH[base + kt * 256];
            bl[kt] = BL[base + kt * 256];
        }
    }

    // combine-phase role: thread owns (chain c_loc, jh j)
    const int c_loc = tid >> 4, j = tid & 15;
    const int kglob = s * 16 + j;                 // h-dim this thread produces
    const int p_kt = kglob >> 5;
    const int p_q = (kglob & 31) >> 3, p_e = kglob & 7;
    const int p_lane = (c_loc & 15) | (p_q << 4);
    const int p_mt = c_loc >> 4;
    const int fb_off = ((p_mt * 8 + p_kt) * 64 + p_lane) * 8 + p_e;
    float* o_out = Mh ? o2 : o1;
    float cst = 0.f;

    const int grp = bid >> 4;                    // (d*2+Mh) in 0..3
    int* gflags = flags + grp * 16;

    for (int t = 0; t < L_; ++t) {
        int l = d ? (L_ - 1 - t) : t;

        // xg gate inputs for this thread (independent of h exchange)
        float xv[4];
        {
            const float* xp = xg + (size_t)(Mh * N_ + c_loc * L_ + l) * 2048
                              + d * 1024 + kglob;
            #pragma unroll
            for (int gg = 0; gg < 4; ++gg) xv[gg] = xp[gg * 256];
        }

        // wait for this group's 16 producers to finish step t-1
        if (t > 0) {
            if (tid < 16) {
                while (__hip_atomic_load(&gflags[tid], __ATOMIC_ACQUIRE,
                                         __HIP_MEMORY_SCOPE_AGENT) < t)
                    __builtin_amdgcn_s_sleep(8);
            }
            __syncthreads();
        }

        // stage fragbuf[d][t&1][Mh] (64 KB) -> LDS
        {
            const uint4* src = (const uint4*)(fragbuf
                + (size_t)((d * 2 + (t & 1)) * 2 + Mh) * FB_USH);
            uint4* dst = (uint4*)smem4;
            #pragma unroll
            for (int r = 0; r < 4; ++r) dst[r * 1024 + tid] = src[r * 1024 + tid];
        }
        __syncthreads();

        // MFMA: preact tile (16 chains x 16 jh) for gate g, 3-term split
        f4v acc = {0.f, 0.f, 0.f, 0.f};
        {
            const s8v* AH = (const s8v*)Ahi;
            const s8v* AL = (const s8v*)Alo;
            #pragma unroll
            for (int kt = 0; kt < 8; ++kt) {
                s8v ah = AH[(mt * 8 + kt) * 64 + lane];
                s8v al = AL[(mt * 8 + kt) * 64 + lane];
                acc = MFMA_B16(ah, bh[kt], acc);
                acc = MFMA_B16(ah, bl[kt], acc);
                acc = MFMA_B16(al, bh[kt], acc);
            }
        }
        __syncthreads();      // all waves done reading A before pre overwrites it

        #pragma unroll
        for (int r = 0; r < 4; ++r)
            pre[(g * 64 + mt * 16 + qq * 4 + r) * 16 + c16] = acc[r];
        __syncthreads();

        // combine: gate math + state update + outputs
        {
            float pi = pre[(0 * 64 + c_loc) * 16 + j] + xv[0];
            float pf = pre[(1 * 64 + c_loc) * 16 + j] + xv[1];
            float pg = pre[(2 * 64 + c_loc) * 16 + j] + xv[2];
            float po = pre[(3 * 64 + c_loc) * 16 + j] + xv[3];
            float si = sigm(pi), sf_ = sigm(pf), so = sigm(po);
            cst = sf_ * cst + si * tanh_fast(pg);
            float h = so * tanh_fast(cst);
            o_out[(size_t)(c_loc * L_ + l) * DH2_ + d * H_ + kglob] = h;
            ushort_t hh = f2bf_rn(h);
            ushort_t hl = f2bf_rn(h - bf2f(hh));
            ushort_t* fb = fragbuf
                + (size_t)((d * 2 + ((t + 1) & 1)) * 2 + Mh) * FB_USH;
            fb[fb_off] = hh;
            fb[16384 + fb_off] = hl;
        }
        __syncthreads();      // drain all threads' stores (barrier waits vmcnt)

        if (tid == 0)
            __hip_atomic_store(&flags[bid], t + 1, __ATOMIC_RELEASE,
                               __HIP_MEMORY_SCOPE_AGENT);
    }
}

// ---------------------------------------------------------------------------
__global__ __launch_bounds__(256) void k_gemm(const float* __restrict__ A,
                                              const float* __restrict__ Bt,
                                              const float* __restrict__ bias,
                                              float* __restrict__ Cout,
                                              int M, int Nn, int K) {
    __shared__ float As[32][65];
    __shared__ float Bs[32][65];
    int tid = threadIdx.x;
    int tx = tid & 15, ty = tid >> 4;
    int r0 = blockIdx.y * 64, c0 = blockIdx.x * 64;
    float acc[4][4] = {};
    for (int kk = 0; kk < K; kk += 32) {
        #pragma unroll
        for (int t = 0; t < 8; ++t) {
            int idx = t * 256 + tid;
            int m = idx >> 5, k = idx & 31;
            As[k][m] = A[(size_t)(r0 + m) * K + kk + k];
            Bs[k][m] = Bt[(size_t)(c0 + m) * K + kk + k];
        }
        __syncthreads();
        #pragma unroll
        for (int k = 0; k < 32; ++k) {
            float a[4], b[4];
            #pragma unroll
            for (int i = 0; i < 4; ++i) a[i] = As[k][ty * 4 + i];
            #pragma unroll
            for (int jj = 0; jj < 4; ++jj) b[jj] = Bs[k][tx * 4 + jj];
            #pragma unroll
            for (int i = 0; i < 4; ++i)
                #pragma unroll
                for (int jj = 0; jj < 4; ++jj) acc[i][jj] += a[i] * b[jj];
        }
        __syncthreads();
    }
    #pragma unroll
    for (int i = 0; i < 4; ++i) {
        int r = r0 + ty * 4 + i;
        #pragma unroll
        for (int jj = 0; jj < 4; ++jj) {
            int c = c0 + tx * 4 + jj;
            float v = acc[i][jj] + (bias ? bias[c] : 0.f);
            Cout[(size_t)r * Nn + c] = v;
        }
    }
}

// ---------------------------------------------------------------------------
__global__ __launch_bounds__(256) void k_big(const float* __restrict__ A,
                                             const float* __restrict__ Bt,
                                             const float* __restrict__ rel,
                                             float* __restrict__ Ebuf,
                                             float* __restrict__ rowpart,
                                             float* __restrict__ colpart) {
    __shared__ float As[32][65];
    __shared__ float Bs[32][65];
    __shared__ float rowred[64][17];
    __shared__ float colred[64][17];
    int tid = threadIdx.x;
    int tx = tid & 15, ty = tid >> 4;
    int r0 = blockIdx.y * 64, c0 = blockIdx.x * 64;
    float acc[4][4] = {};
    for (int kk = 0; kk < DH2_; kk += 32) {
        #pragma unroll
        for (int t = 0; t < 8; ++t) {
            int idx = t * 256 + tid;
            int m = idx >> 5, k = idx & 31;
            As[k][m] = A[(size_t)(r0 + m) * DH2_ + kk + k];
            Bs[k][m] = Bt[(size_t)(c0 + m) * DH2_ + kk + k];
        }
        __syncthreads();
        #pragma unroll
        for (int k = 0; k < 32; ++k) {
            float a[4], b[4];
            #pragma unroll
            for (int i = 0; i < 4; ++i) a[i] = As[k][ty * 4 + i];
            #pragma unroll
            for (int jj = 0; jj < 4; ++jj) b[jj] = Bs[k][tx * 4 + jj];
            #pragma unroll
            for (int i = 0; i < 4; ++i)
                #pragma unroll
                for (int jj = 0; jj < 4; ++jj) acc[i][jj] += a[i] * b[jj];
        }
        __syncthreads();
    }
    float rsum[4] = {0.f, 0.f, 0.f, 0.f};
    float csum[4] = {0.f, 0.f, 0.f, 0.f};
    #pragma unroll
    for (int i = 0; i < 4; ++i) {
        int r = r0 + ty * 4 + i;
        int bi = r / 80, li = r - bi * 80;
        #pragma unroll
        for (int jj = 0; jj < 4; ++jj) {
            int c = c0 + tx * 4 + jj;
            int bj = c / 80, lj = c - bj * 80;
            float v = tanhf(acc[i][jj]);
            if (bi == bj) v += rel[li * 80 + lj];
            float e = expf(v);
            Ebuf[(size_t)r * N_ + c] = e;
            rsum[i] += e;
            csum[jj] += e;
        }
    }
    #pragma unroll
    for (int i = 0; i < 4; ++i) rowred[ty * 4 + i][tx] = rsum[i];
    #pragma unroll
    for (int jj = 0; jj < 4; ++jj) colred[tx * 4 + jj][ty] = csum[jj];
    __syncthreads();
    if (tid < 64) {
        float sum = 0.f;
        #pragma unroll
        for (int t = 0; t < 16; ++t) sum += rowred[tid][t];
        rowpart[(size_t)blockIdx.x * N_ + r0 + tid] = sum;
    } else if (tid < 128) {
        int n = tid - 64;
        float sum = 0.f;
        #pragma unroll
        for (int t = 0; t < 16; ++t) sum += colred[n][t];
        colpart[(size_t)blockIdx.y * N_ + c0 + n] = sum;
    }
}

// ---------------------------------------------------------------------------
__global__ void k_redsum(const float* __restrict__ rowpart, const float* __restrict__ colpart,
                         float* __restrict__ rowinv, float* __restrict__ colinv) {
    int i = blockIdx.x * blockDim.x + threadIdx.x;
    if (i < N_) {
        float rs = 0.f, cs = 0.f;
        for (int t = 0; t < 80; ++t) {
            rs += rowpart[(size_t)t * N_ + i];
            cs += colpart[(size_t)t * N_ + i];
        }
        rowinv[i] = 1.f / rs;
        colinv[i] = 1.f / cs;
    }
}

__global__ __launch_bounds__(256) void k_sf2(const float* __restrict__ Ebuf,
                                             const float* __restrict__ colinv,
                                             float* __restrict__ sf2) {
    int i = blockIdx.x;
    float p = 0.f;
    for (int jj = threadIdx.x; jj < N_; jj += 256)
        p += Ebuf[(size_t)i * N_ + jj] * colinv[jj];
    __shared__ float red[256];
    red[threadIdx.x] = p;
    __syncthreads();
    for (int ss = 128; ss > 0; ss >>= 1) {
        if (threadIdx.x < ss) red[threadIdx.x] += red[threadIdx.x + ss];
        __syncthreads();
    }
    if (threadIdx.x == 0) sf2[i] = red[0] * (1.f / N_);
}

__global__ __launch_bounds__(256) void k_sf1part(const float* __restrict__ Ebuf,
                                                 const float* __restrict__ rowinv,
                                                 float* __restrict__ sf1part) {
    int ti = blockIdx.x;
    int i0 = ti * 64;
    float acc[20] = {};
    for (int ii = 0; ii < 64; ++ii) {
        float inv = rowinv[i0 + ii];
        const float* row = Ebuf + (size_t)(i0 + ii) * N_;
        #pragma unroll
        for (int q = 0; q < 20; ++q) acc[q] += row[threadIdx.x + q * 256] * inv;
    }
    #pragma unroll
    for (int q = 0; q < 20; ++q)
        sf1part[(size_t)ti * N_ + threadIdx.x + q * 256] = acc[q];
}

__global__ void k_sf1red(const float* __restrict__ sf1part, float* __restrict__ sf1) {
    int jj = blockIdx.x * blockDim.x + threadIdx.x;
    if (jj < N_) {
        float s = 0.f;
        for (int t = 0; t < 80; ++t) s += sf1part[(size_t)t * N_ + jj];
        sf1[jj] = s * (1.f / N_);
    }
}

// ---------------------------------------------------------------------------
__global__ void k_bnstats(const float* __restrict__ o1, const float* __restrict__ o2,
                          const float* __restrict__ sf1, const float* __restrict__ sf2,
                          float* __restrict__ bnmu, float* __restrict__ bnrstd) {
    int f = blockIdx.x * 256 + threadIdx.x;
    int seg = f / (L_ * DH2_);
    int rem = f - seg * (L_ * DH2_);
    int l = rem >> 9, hh = rem & 511;
    const float* t = seg ? o2 : o1;
    const float* sf = seg ? sf1 : sf2;
    float s = 0.f;
    for (int b = 0; b < B_; ++b) {
        int row = b * L_ + l;
        s += t[(size_t)row * DH2_ + hh] * sf[row];
    }
    float mu = s * (1.f / B_);
    float v = 0.f;
    for (int b = 0; b < B_; ++b) {
        int row = b * L_ + l;
        float x = t[(size_t)row * DH2_ + hh] * sf[row] - mu;
        v += x * x;
    }
    v *= (1.f / B_);
    bnmu[f] = mu;
    bnrstd[f] = rsqrtf(v + EPS_);
}

__global__ __launch_bounds__(256) void k_logits(const float* __restrict__ o1,
                                                const float* __restrict__ o2,
                                                const float* __restrict__ sf1,
                                                const float* __restrict__ sf2,
                                                const float* __restrict__ bnmu,
                                                const float* __restrict__ bnrstd,
                                                const float* __restrict__ gamma,
                                                const float* __restrict__ beta,
                                                const float* __restrict__ fcW,
                                                const float* __restrict__ fcb,
                                                float* __restrict__ dout) {
    int b = blockIdx.x;
    int tid = threadIdx.x;
    float acc[4] = {0.f, 0.f, 0.f, 0.f};
    for (int f = tid; f < DF_; f += 256) {
        int seg = f / (L_ * DH2_);
        int rem = f - seg * (L_ * DH2_);
        int l = rem >> 9, hh = rem & 511;
        int row = b * L_ + l;
        float val = (seg ? o2 : o1)[(size_t)row * DH2_ + hh] * (seg ? sf1 : sf2)[row];
        float xn = (val - bnmu[f]) * bnrstd[f] * gamma[f] + beta[f];
        #pragma unroll
        for (int c = 0; c < 4; ++c) acc[c] += xn * fcW[(size_t)c * DF_ + f];
    }
    __shared__ float red[4][257];
    #pragma unroll
    for (int c = 0; c < 4; ++c) red[c][tid] = acc[c];
    __syncthreads();
    for (int ss = 128; ss > 0; ss >>= 1) {
        if (tid < ss)
            #pragma unroll
            for (int c = 0; c < 4; ++c) red[c][tid] += red[c][tid + ss];
        __syncthreads();
    }
    if (tid == 0) {
        float lg[4], mx = -1e30f;
        #pragma unroll
        for (int c = 0; c < 4; ++c) { lg[c] = red[c][0] + fcb[c]; mx = fmaxf(mx, lg[c]); }
        float se = 0.f;
        #pragma unroll
        for (int c = 0; c < 4; ++c) se += expf(lg[c] - mx);
        float lse = mx + logf(se);
        #pragma unroll
        for (int c = 0; c < 4; ++c) dout[b * 4 + c] = lg[c] - lse;
    }
}

// ---------------------------------------------------------------------------
extern "C" void kernel_launch(void* const* d_in, const int* in_sizes, int n_in,
                              void* d_out, int out_size, void* d_ws, size_t ws_size,
                              hipStream_t stream) {
    const int* arg1 = (const int*)d_in[0];
    const int* arg2 = (const int*)d_in[1];
    const float* tE1 = (const float*)d_in[3];
    const float* tE2 = (const float*)d_in[4];
    const float* table = (const float*)d_in[5];
    const float* Wih_f = (const float*)d_in[6];
    const float* Whh_f = (const float*)d_in[7];
    const float* bih_f = (const float*)d_in[8];
    const float* bhh_f = (const float*)d_in[9];
    const float* Wih_b = (const float*)d_in[10];
    const float* Whh_b = (const float*)d_in[11];
    const float* bih_b = (const float*)d_in[12];
    const float* bhh_b = (const float*)d_in[13];
    const float* R = (const float*)d_in[14];
    const float* gamma = (const float*)d_in[15];
    const float* beta = (const float*)d_in[16];
    const float* fcW = (const float*)d_in[17];
    const float* fcb = (const float*)d_in[18];
    float* dout = (float*)d_out;

    float* ws = (float*)d_ws;
    size_t off = 0;
    auto alloc = [&](size_t n) { float* p = ws + off; off += n; return p; };

    float* rel = alloc(80 * 80);
    float* e = alloc((size_t)2 * N_ * E_);
    float* Wcat = alloc((size_t)2 * G4_ * E_);
    float* bcat = alloc(2 * G4_);
    float* Rt = alloc(512 * 512);
    float* o1 = alloc((size_t)N_ * DH2_);
    float* o2 = alloc((size_t)N_ * DH2_);
    float* u = alloc((size_t)N_ * DH2_);
    float* rowpart = alloc((size_t)80 * N_);
    float* colpart = alloc((size_t)80 * N_);
    float* rowinv = alloc(N_);
    float* colinv = alloc(N_);
    float* sf1part = alloc((size_t)80 * N_);
    float* sf1 = alloc(N_);
    float* sf2 = alloc(N_);
    float* bnmu = alloc(DF_);
    float* bnrstd = alloc(DF_);
    ushort_t* Bhi = (ushort_t*)alloc(262144);        // 512 KB
    ushort_t* Blo = (ushort_t*)alloc(262144);        // 512 KB
    ushort_t* fragbuf = (ushort_t*)alloc(131072);    // 512 KB (8 x 64 KB)
    int* flags = (int*)alloc(64);
    float* xg = alloc((size_t)N_ * N_);   // aliased with Ebuf
    float* Ebuf = xg;

    k_rel<<<1, 256, 0, stream>>>(tE1, tE2, rel);
    k_embed<<<2 * N_, 256, 0, stream>>>(arg1, arg2, table, e);
    k_pack<<<2048, 256, 0, stream>>>(Wih_f, Wih_b, bih_f, bhh_f, bih_b, bhh_b, R,
                                     Wcat, bcat, Rt);
    k_packw<<<2048, 256, 0, stream>>>(Whh_f, Whh_b, Bhi, Blo);
    k_initlstm<<<64, 256, 0, stream>>>(fragbuf, flags);
    k_gemm<<<dim3(2 * G4_ / 64, 2 * N_ / 64), 256, 0, stream>>>(
        e, Wcat, bcat, xg, 2 * N_, 2 * G4_, E_);
    k_lstm4<<<64, 1024, 0, stream>>>(xg, Bhi, Blo, o1, o2, fragbuf, flags);
    k_gemm<<<dim3(DH2_ / 64, N_ / 64), 256, 0, stream>>>(
        o1, Rt, nullptr, u, N_, DH2_, DH2_);
    k_big<<<dim3(N_ / 64, N_ / 64), 256, 0, stream>>>(u, o2, rel, Ebuf, rowpart, colpart);
    k_redsum<<<(N_ + 255) / 256, 256, 0, stream>>>(rowpart, colpart, rowinv, colinv);
    k_sf2<<<N_, 256, 0, stream>>>(Ebuf, colinv, sf2);
    k_sf1part<<<80, 256, 0, stream>>>(Ebuf, rowinv, sf1part);
    k_sf1red<<<(N_ + 255) / 256, 256, 0, stream>>>(sf1part, sf1);
    k_bnstats<<<DF_ / 256, 256, 0, stream>>>(o1, o2, sf1, sf2, bnmu, bnrstd);
    k_logits<<<B_, 256, 0, stream>>>(o1, o2, sf1, sf2, bnmu, bnrstd, gamma, beta,
                                     fcW, fcb, dout);
}

// Round 5
// 1128.334 us; speedup vs baseline: 3.6352x; 1.3269x over previous
//
#include <hip/hip_runtime.h>
#include <cstddef>
#include <cstdint>

typedef unsigned short ushort_t;

constexpr int B_ = 64, L_ = 80, E_ = 256, H_ = 256, C_ = 4, DT_ = 100;
constexpr int N_ = B_ * L_;          // 5120
constexpr int G4_ = 4 * H_;          // 1024
constexpr int DH2_ = 2 * H_;         // 512
constexpr int DF_ = 4 * L_ * H_;     // 81920
constexpr float EPS_ = 1e-5f;
constexpr int FB_USH = 32768;        // ushorts per (d,par,Mh) fragment buffer (64 KB)

typedef short s8v __attribute__((ext_vector_type(8)));
typedef float f4v __attribute__((ext_vector_type(4)));
typedef ushort_t us8 __attribute__((ext_vector_type(8)));

__device__ inline ushort_t f2bf_rn(float x) {
    uint32_t u = __builtin_bit_cast(uint32_t, x);
    uint32_t r = (u + 0x7fffu + ((u >> 16) & 1u)) >> 16;
    return (ushort_t)r;
}
__device__ inline float bf2f(ushort_t h) {
    uint32_t u = ((uint32_t)h) << 16;
    return __builtin_bit_cast(float, u);
}
__device__ inline float rcpf(float x) { return __builtin_amdgcn_rcpf(x); }
__device__ inline float sigm(float x) { return rcpf(1.f + __expf(-x)); }
__device__ inline float tanh_fast(float x) {
    float e2 = __expf(2.f * x);
    return 1.f - 2.f * rcpf(1.f + e2);
}

// ---------------------------------------------------------------------------
__global__ void k_rel(const float* __restrict__ tE1, const float* __restrict__ tE2,
                      float* __restrict__ rel) {
    __shared__ float m1[80], m2[80];
    int t = threadIdx.x;
    if (t < 80) {
        float s = 0.f;
        for (int k = 0; k < DT_; ++k) s += tE1[t * DT_ + k];
        m1[t] = s * (1.0f / DT_);
    } else if (t < 160) {
        int i = t - 80;
        float s = 0.f;
        for (int k = 0; k < DT_; ++k) s += tE2[i * DT_ + k];
        m2[i] = s * (1.0f / DT_);
    }
    __syncthreads();
    for (int idx = t; idx < 80 * 80; idx += blockDim.x)
        rel[idx] = tanhf(m1[idx / 80] - m2[idx % 80]);
}

// ---------------------------------------------------------------------------
__global__ void k_embed(const int* __restrict__ arg1, const int* __restrict__ arg2,
                        const float* __restrict__ table, float* __restrict__ e) {
    int r = blockIdx.x;                 // 0..2N-1
    int rr = (r >= N_) ? (r - N_) : r;
    int idx = (r >= N_) ? arg2[rr] : arg1[rr];
    e[(size_t)r * E_ + threadIdx.x] = table[(size_t)idx * E_ + threadIdx.x];
}

// ---------------------------------------------------------------------------
__global__ void k_pack(const float* __restrict__ Wih_f, const float* __restrict__ Wih_b,
                       const float* __restrict__ bih_f, const float* __restrict__ bhh_f,
                       const float* __restrict__ bih_b, const float* __restrict__ bhh_b,
                       const float* __restrict__ R,
                       float* __restrict__ Wcat, float* __restrict__ bcat,
                       float* __restrict__ Rt) {
    int i = blockIdx.x * blockDim.x + threadIdx.x;
    if (i < 2 * G4_ * E_)
        Wcat[i] = (i < G4_ * E_) ? Wih_f[i] : Wih_b[i - G4_ * E_];
    if (i < 2 * G4_)
        bcat[i] = (i < G4_) ? (bih_f[i] + bhh_f[i]) : (bih_b[i - G4_] + bhh_b[i - G4_]);
    if (i < 512 * 512) {
        int m = i >> 9, k = i & 511;
        Rt[i] = R[k * 512 + m];
    }
}

// ---------------------------------------------------------------------------
// Pack Whh into MFMA B-fragment order, split bf16 hi/lo.
__global__ void k_packw(const float* __restrict__ Whh_f, const float* __restrict__ Whh_b,
                        ushort_t* __restrict__ Bhi, ushort_t* __restrict__ Blo) {
    int idx = blockIdx.x * 256 + threadIdx.x;      // total 524288
    if (idx >= 2 * 16 * 8 * 4 * 64 * 8) return;
    int e = idx & 7;
    int lane = (idx >> 3) & 63;
    int g = (idx >> 9) & 3;
    int kt = (idx >> 11) & 7;
    int w = (idx >> 14) & 15;
    int d = idx >> 18;
    int c = lane & 15, q = lane >> 4;
    int row = g * 256 + w * 16 + c;
    int k = kt * 32 + q * 8 + e;
    const float* W = d ? Whh_b : Whh_f;
    float v = W[row * 256 + k];
    ushort_t hi = f2bf_rn(v);
    Bhi[idx] = hi;
    Blo[idx] = f2bf_rn(v - bf2f(hi));
}

// ---------------------------------------------------------------------------
__global__ void k_initlstm(ushort_t* __restrict__ fragbuf, int* __restrict__ flags) {
    int i = blockIdx.x * 256 + threadIdx.x;
    if (i < 64) flags[i] = 0;
    uint4* p = (uint4*)fragbuf;          // 512 KB total = 32768 uint4
    for (int jj = i; jj < 32768; jj += gridDim.x * 256)
        p[jj] = make_uint4(0u, 0u, 0u, 0u);
}

// ---------------------------------------------------------------------------
// Persistent flag-dataflow LSTM. 64 blocks x 1024 threads. (Round-4, kept.)
#define MFMA_B16(a, b, c) __builtin_amdgcn_mfma_f32_16x16x32_bf16((a), (b), (c), 0, 0, 0)

__global__ __launch_bounds__(1024, 4) void k_lstm4(
        const float* __restrict__ xg,
        const ushort_t* __restrict__ Bhi, const ushort_t* __restrict__ Blo,
        float* __restrict__ o1, float* __restrict__ o2,
        ushort_t* __restrict__ fragbuf, int* __restrict__ flags) {
    const int bid = blockIdx.x;
    const int s = bid & 15;
    const int Mh = (bid >> 4) & 1;
    const int d = bid >> 5;
    const int tid = threadIdx.x;
    const int w_id = tid >> 6, lane = tid & 63;
    const int g = w_id & 3, mt = w_id >> 2;
    const int c16 = lane & 15, qq = lane >> 4;

    __shared__ uint32_t smem4[16384];            // 64 KB
    ushort_t* Ahi = (ushort_t*)smem4;            // [mt4][kt8][lane64][e8]
    ushort_t* Alo = Ahi + 16384;                 // +32 KB
    float* pre = (float*)smem4;                  // [g4][c64][j16] (aliases Ahi)

    s8v bh[8], bl[8];
    {
        const s8v* BH = (const s8v*)Bhi;
        const s8v* BL = (const s8v*)Blo;
        int base = (d * 16 + s) * 2048 + g * 64 + lane;
        #pragma unroll
        for (int kt = 0; kt < 8; ++kt) {
            bh[kt] = BH[base + kt * 256];
            bl[kt] = BL[base + kt * 256];
        }
    }

    const int c_loc = tid >> 4, j = tid & 15;
    const int kglob = s * 16 + j;
    const int p_kt = kglob >> 5;
    const int p_q = (kglob & 31) >> 3, p_e = kglob & 7;
    const int p_lane = (c_loc & 15) | (p_q << 4);
    const int p_mt = c_loc >> 4;
    const int fb_off = ((p_mt * 8 + p_kt) * 64 + p_lane) * 8 + p_e;
    float* o_out = Mh ? o2 : o1;
    float cst = 0.f;

    const int grp = bid >> 4;
    int* gflags = flags + grp * 16;

    for (int t = 0; t < L_; ++t) {
        int l = d ? (L_ - 1 - t) : t;

        float xv[4];
        {
            const float* xp = xg + (size_t)(Mh * N_ + c_loc * L_ + l) * 2048
                              + d * 1024 + kglob;
            #pragma unroll
            for (int gg = 0; gg < 4; ++gg) xv[gg] = xp[gg * 256];
        }

        if (t > 0) {
            if (tid < 16) {
                while (__hip_atomic_load(&gflags[tid], __ATOMIC_ACQUIRE,
                                         __HIP_MEMORY_SCOPE_AGENT) < t)
                    __builtin_amdgcn_s_sleep(8);
            }
            __syncthreads();
        }

        {
            const uint4* src = (const uint4*)(fragbuf
                + (size_t)((d * 2 + (t & 1)) * 2 + Mh) * FB_USH);
            uint4* dst = (uint4*)smem4;
            #pragma unroll
            for (int r = 0; r < 4; ++r) dst[r * 1024 + tid] = src[r * 1024 + tid];
        }
        __syncthreads();

        f4v acc = {0.f, 0.f, 0.f, 0.f};
        {
            const s8v* AH = (const s8v*)Ahi;
            const s8v* AL = (const s8v*)Alo;
            #pragma unroll
            for (int kt = 0; kt < 8; ++kt) {
                s8v ah = AH[(mt * 8 + kt) * 64 + lane];
                s8v al = AL[(mt * 8 + kt) * 64 + lane];
                acc = MFMA_B16(ah, bh[kt], acc);
                acc = MFMA_B16(ah, bl[kt], acc);
                acc = MFMA_B16(al, bh[kt], acc);
            }
        }
        __syncthreads();

        #pragma unroll
        for (int r = 0; r < 4; ++r)
            pre[(g * 64 + mt * 16 + qq * 4 + r) * 16 + c16] = acc[r];
        __syncthreads();

        {
            float pi = pre[(0 * 64 + c_loc) * 16 + j] + xv[0];
            float pf = pre[(1 * 64 + c_loc) * 16 + j] + xv[1];
            float pg = pre[(2 * 64 + c_loc) * 16 + j] + xv[2];
            float po = pre[(3 * 64 + c_loc) * 16 + j] + xv[3];
            float si = sigm(pi), sf_ = sigm(pf), so = sigm(po);
            cst = sf_ * cst + si * tanh_fast(pg);
            float h = so * tanh_fast(cst);
            o_out[(size_t)(c_loc * L_ + l) * DH2_ + d * H_ + kglob] = h;
            ushort_t hh = f2bf_rn(h);
            ushort_t hl = f2bf_rn(h - bf2f(hh));
            ushort_t* fb = fragbuf
                + (size_t)((d * 2 + ((t + 1) & 1)) * 2 + Mh) * FB_USH;
            fb[fb_off] = hh;
            fb[16384 + fb_off] = hl;
        }
        __syncthreads();

        if (tid == 0)
            __hip_atomic_store(&flags[bid], t + 1, __ATOMIC_RELEASE,
                               __HIP_MEMORY_SCOPE_AGENT);
    }
}

// ---------------------------------------------------------------------------
__global__ __launch_bounds__(256) void k_gemm(const float* __restrict__ A,
                                              const float* __restrict__ Bt,
                                              const float* __restrict__ bias,
                                              float* __restrict__ Cout,
                                              int M, int Nn, int K) {
    __shared__ float As[32][65];
    __shared__ float Bs[32][65];
    int tid = threadIdx.x;
    int tx = tid & 15, ty = tid >> 4;
    int r0 = blockIdx.y * 64, c0 = blockIdx.x * 64;
    float acc[4][4] = {};
    for (int kk = 0; kk < K; kk += 32) {
        #pragma unroll
        for (int t = 0; t < 8; ++t) {
            int idx = t * 256 + tid;
            int m = idx >> 5, k = idx & 31;
            As[k][m] = A[(size_t)(r0 + m) * K + kk + k];
            Bs[k][m] = Bt[(size_t)(c0 + m) * K + kk + k];
        }
        __syncthreads();
        #pragma unroll
        for (int k = 0; k < 32; ++k) {
            float a[4], b[4];
            #pragma unroll
            for (int i = 0; i < 4; ++i) a[i] = As[k][ty * 4 + i];
            #pragma unroll
            for (int jj = 0; jj < 4; ++jj) b[jj] = Bs[k][tx * 4 + jj];
            #pragma unroll
            for (int i = 0; i < 4; ++i)
                #pragma unroll
                for (int jj = 0; jj < 4; ++jj) acc[i][jj] += a[i] * b[jj];
        }
        __syncthreads();
    }
    #pragma unroll
    for (int i = 0; i < 4; ++i) {
        int r = r0 + ty * 4 + i;
        #pragma unroll
        for (int jj = 0; jj < 4; ++jj) {
            int c = c0 + tx * 4 + jj;
            float v = acc[i][jj] + (bias ? bias[c] : 0.f);
            Cout[(size_t)r * Nn + c] = v;
        }
    }
}

// ---------------------------------------------------------------------------
// Convert u and t2 to split-bf16 (hi/lo) row-major [N][512] arrays.
__global__ void k_cvt(const float* __restrict__ u, const float* __restrict__ t2,
                      ushort_t* __restrict__ uhi, ushort_t* __restrict__ ulo,
                      ushort_t* __restrict__ vhi, ushort_t* __restrict__ vlo) {
    int i = blockIdx.x * 256 + threadIdx.x;
    if (i < N_ * DH2_) {
        float a = u[i];
        ushort_t h = f2bf_rn(a);
        uhi[i] = h;
        ulo[i] = f2bf_rn(a - bf2f(h));
        float b = t2[i];
        ushort_t h2 = f2bf_rn(b);
        vhi[i] = h2;
        vlo[i] = f2bf_rn(b - bf2f(h2));
    }
}

// ---------------------------------------------------------------------------
// MFMA k_big: last = tanh(u t2^T) + kg; E = exp(last); tile row/col sums.
// 128x128 tile, BK=32, 4 waves (2x2), split-bf16 (3 MFMAs/product).
// LDS layout per plane: [q(4)][row(128)][8 ushorts] -- 16B chunks, row
// stride 16 B => <=2-way bank aliasing (free). Planes: 0=Ahi 1=Alo 2=Bhi 3=Blo.
__global__ __launch_bounds__(256) void k_bigm(
        const ushort_t* __restrict__ uhi, const ushort_t* __restrict__ ulo,
        const ushort_t* __restrict__ vhi, const ushort_t* __restrict__ vlo,
        const float* __restrict__ rel, float* __restrict__ Ebuf,
        float* __restrict__ rowpart, float* __restrict__ colpart) {
    __shared__ ushort_t smpool[4][4096];        // 32 KB
    const int tid = threadIdx.x;
    const int w = tid >> 6, lane = tid & 63;
    const int wr = w >> 1, wc = w & 1;
    const int c16 = lane & 15, q4 = lane >> 4;
    const int r0 = blockIdx.y * 128, c0 = blockIdx.x * 128;

    f4v acc[4][4] = {};

    const ushort_t* planes[4] = {
        uhi + (size_t)r0 * DH2_, ulo + (size_t)r0 * DH2_,
        vhi + (size_t)c0 * DH2_, vlo + (size_t)c0 * DH2_ };

    for (int kk = 0; kk < 16; ++kk) {
        // stage 4 planes of 128x32 bf16
        #pragma unroll
        for (int p = 0; p < 4; ++p) {
            const ushort_t* src = planes[p] + kk * 32;
            #pragma unroll
            for (int it = 0; it < 2; ++it) {
                int idx = it * 256 + tid;           // 0..511
                int row = idx >> 2, q = idx & 3;
                *(us8*)&smpool[p][(q * 128 + row) * 8] =
                    *(const us8*)&src[(size_t)row * DH2_ + q * 8];
            }
        }
        __syncthreads();

        s8v ah[4], al[4], bhv[4], blv[4];
        #pragma unroll
        for (int mi = 0; mi < 4; ++mi) {
            int ar = wr * 64 + mi * 16 + c16;
            ah[mi] = *(const s8v*)&smpool[0][(q4 * 128 + ar) * 8];
            al[mi] = *(const s8v*)&smpool[1][(q4 * 128 + ar) * 8];
        }
        #pragma unroll
        for (int ni = 0; ni < 4; ++ni) {
            int br = wc * 64 + ni * 16 + c16;
            bhv[ni] = *(const s8v*)&smpool[2][(q4 * 128 + br) * 8];
            blv[ni] = *(const s8v*)&smpool[3][(q4 * 128 + br) * 8];
        }
        #pragma unroll
        for (int mi = 0; mi < 4; ++mi)
            #pragma unroll
            for (int ni = 0; ni < 4; ++ni) {
                acc[mi][ni] = MFMA_B16(ah[mi], bhv[ni], acc[mi][ni]);
                acc[mi][ni] = MFMA_B16(ah[mi], blv[ni], acc[mi][ni]);
                acc[mi][ni] = MFMA_B16(al[mi], bhv[ni], acc[mi][ni]);
            }
        __syncthreads();
    }

    // fused epilogue: tanh -> +rel -> exp -> store -> partial sums
    float* rowred = (float*)&smpool[0][0];      // [128][32]
    float* colred = rowred + 128 * 32;          // [128][8]

    int gcolv[4], bjv[4], ljv[4];
    #pragma unroll
    for (int ni = 0; ni < 4; ++ni) {
        int coll = wc * 64 + ni * 16 + c16;
        gcolv[ni] = c0 + coll;
        bjv[ni] = gcolv[ni] / 80;
        ljv[ni] = gcolv[ni] - bjv[ni] * 80;
    }
    float csumv[4] = {0.f, 0.f, 0.f, 0.f};
    #pragma unroll
    for (int mi = 0; mi < 4; ++mi) {
        #pragma unroll
        for (int rg = 0; rg < 4; ++rg) {
            int rowl = wr * 64 + mi * 16 + q4 * 4 + rg;
            int grow = r0 + rowl;
            int bi = grow / 80, li = grow - bi * 80;
            float rsum = 0.f;
            #pragma unroll
            for (int ni = 0; ni < 4; ++ni) {
                float v = tanhf(acc[mi][ni][rg]);
                if (bi == bjv[ni]) v += rel[li * 80 + ljv[ni]];
                float ev = __expf(v);
                Ebuf[(size_t)grow * N_ + gcolv[ni]] = ev;
                rsum += ev;
                csumv[ni] += ev;
            }
            rowred[rowl * 32 + wc * 16 + c16] = rsum;
        }
    }
    #pragma unroll
    for (int ni = 0; ni < 4; ++ni) {
        int coll = wc * 64 + ni * 16 + c16;
        colred[coll * 8 + wr * 4 + q4] = csumv[ni];
    }
    __syncthreads();
    if (tid < 128) {
        float ssum = 0.f;
        #pragma unroll
        for (int t = 0; t < 32; ++t) ssum += rowred[tid * 32 + t];
        rowpart[(size_t)blockIdx.x * N_ + r0 + tid] = ssum;
    } else {
        int c = tid - 128;
        float ssum = 0.f;
        #pragma unroll
        for (int t = 0; t < 8; ++t) ssum += colred[c * 8 + t];
        colpart[(size_t)blockIdx.y * N_ + c0 + c] = ssum;
    }
}

// ---------------------------------------------------------------------------
__global__ void k_redsum(const float* __restrict__ rowpart, const float* __restrict__ colpart,
                         float* __restrict__ rowinv, float* __restrict__ colinv) {
    int i = blockIdx.x * blockDim.x + threadIdx.x;
    if (i < N_) {
        float rs = 0.f, cs = 0.f;
        for (int t = 0; t < 40; ++t) {
            rs += rowpart[(size_t)t * N_ + i];
            cs += colpart[(size_t)t * N_ + i];
        }
        rowinv[i] = 1.f / rs;
        colinv[i] = 1.f / cs;
    }
}

__global__ __launch_bounds__(256) void k_sf2(const float* __restrict__ Ebuf,
                                             const float* __restrict__ colinv,
                                             float* __restrict__ sf2) {
    int i = blockIdx.x;
    float p = 0.f;
    for (int jj = threadIdx.x; jj < N_; jj += 256)
        p += Ebuf[(size_t)i * N_ + jj] * colinv[jj];
    __shared__ float red[256];
    red[threadIdx.x] = p;
    __syncthreads();
    for (int ss = 128; ss > 0; ss >>= 1) {
        if (threadIdx.x < ss) red[threadIdx.x] += red[threadIdx.x + ss];
        __syncthreads();
    }
    if (threadIdx.x == 0) sf2[i] = red[0] * (1.f / N_);
}

__global__ __launch_bounds__(256) void k_sf1part(const float* __restrict__ Ebuf,
                                                 const float* __restrict__ rowinv,
                                                 float* __restrict__ sf1part) {
    int ti = blockIdx.x;
    int i0 = ti * 64;
    float acc[20] = {};
    for (int ii = 0; ii < 64; ++ii) {
        float inv = rowinv[i0 + ii];
        const float* row = Ebuf + (size_t)(i0 + ii) * N_;
        #pragma unroll
        for (int q = 0; q < 20; ++q) acc[q] += row[threadIdx.x + q * 256] * inv;
    }
    #pragma unroll
    for (int q = 0; q < 20; ++q)
        sf1part[(size_t)ti * N_ + threadIdx.x + q * 256] = acc[q];
}

__global__ void k_sf1red(const float* __restrict__ sf1part, float* __restrict__ sf1) {
    int jj = blockIdx.x * blockDim.x + threadIdx.x;
    if (jj < N_) {
        float s = 0.f;
        for (int t = 0; t < 80; ++t) s += sf1part[(size_t)t * N_ + jj];
        sf1[jj] = s * (1.f / N_);
    }
}

// ---------------------------------------------------------------------------
__global__ void k_bnstats(const float* __restrict__ o1, const float* __restrict__ o2,
                          const float* __restrict__ sf1, const float* __restrict__ sf2,
                          float* __restrict__ bnmu, float* __restrict__ bnrstd) {
    int f = blockIdx.x * 256 + threadIdx.x;
    int seg = f / (L_ * DH2_);
    int rem = f - seg * (L_ * DH2_);
    int l = rem >> 9, hh = rem & 511;
    const float* t = seg ? o2 : o1;
    const float* sf = seg ? sf1 : sf2;
    float s = 0.f;
    for (int b = 0; b < B_; ++b) {
        int row = b * L_ + l;
        s += t[(size_t)row * DH2_ + hh] * sf[row];
    }
    float mu = s * (1.f / B_);
    float v = 0.f;
    for (int b = 0; b < B_; ++b) {
        int row = b * L_ + l;
        float x = t[(size_t)row * DH2_ + hh] * sf[row] - mu;
        v += x * x;
    }
    v *= (1.f / B_);
    bnmu[f] = mu;
    bnrstd[f] = rsqrtf(v + EPS_);
}

__global__ __launch_bounds__(256) void k_logits(const float* __restrict__ o1,
                                                const float* __restrict__ o2,
                                                const float* __restrict__ sf1,
                                                const float* __restrict__ sf2,
                                                const float* __restrict__ bnmu,
                                                const float* __restrict__ bnrstd,
                                                const float* __restrict__ gamma,
                                                const float* __restrict__ beta,
                                                const float* __restrict__ fcW,
                                                const float* __restrict__ fcb,
                                                float* __restrict__ dout) {
    int b = blockIdx.x;
    int tid = threadIdx.x;
    float acc[4] = {0.f, 0.f, 0.f, 0.f};
    for (int f = tid; f < DF_; f += 256) {
        int seg = f / (L_ * DH2_);
        int rem = f - seg * (L_ * DH2_);
        int l = rem >> 9, hh = rem & 511;
        int row = b * L_ + l;
        float val = (seg ? o2 : o1)[(size_t)row * DH2_ + hh] * (seg ? sf1 : sf2)[row];
        float xn = (val - bnmu[f]) * bnrstd[f] * gamma[f] + beta[f];
        #pragma unroll
        for (int c = 0; c < 4; ++c) acc[c] += xn * fcW[(size_t)c * DF_ + f];
    }
    __shared__ float red[4][257];
    #pragma unroll
    for (int c = 0; c < 4; ++c) red[c][tid] = acc[c];
    __syncthreads();
    for (int ss = 128; ss > 0; ss >>= 1) {
        if (tid < ss)
            #pragma unroll
            for (int c = 0; c < 4; ++c) red[c][tid] += red[c][tid + ss];
        __syncthreads();
    }
    if (tid == 0) {
        float lg[4], mx = -1e30f;
        #pragma unroll
        for (int c = 0; c < 4; ++c) { lg[c] = red[c][0] + fcb[c]; mx = fmaxf(mx, lg[c]); }
        float se = 0.f;
        #pragma unroll
        for (int c = 0; c < 4; ++c) se += expf(lg[c] - mx);
        float lse = mx + logf(se);
        #pragma unroll
        for (int c = 0; c < 4; ++c) dout[b * 4 + c] = lg[c] - lse;
    }
}

// ---------------------------------------------------------------------------
extern "C" void kernel_launch(void* const* d_in, const int* in_sizes, int n_in,
                              void* d_out, int out_size, void* d_ws, size_t ws_size,
                              hipStream_t stream) {
    const int* arg1 = (const int*)d_in[0];
    const int* arg2 = (const int*)d_in[1];
    const float* tE1 = (const float*)d_in[3];
    const float* tE2 = (const float*)d_in[4];
    const float* table = (const float*)d_in[5];
    const float* Wih_f = (const float*)d_in[6];
    const float* Whh_f = (const float*)d_in[7];
    const float* bih_f = (const float*)d_in[8];
    const float* bhh_f = (const float*)d_in[9];
    const float* Wih_b = (const float*)d_in[10];
    const float* Whh_b = (const float*)d_in[11];
    const float* bih_b = (const float*)d_in[12];
    const float* bhh_b = (const float*)d_in[13];
    const float* R = (const float*)d_in[14];
    const float* gamma = (const float*)d_in[15];
    const float* beta = (const float*)d_in[16];
    const float* fcW = (const float*)d_in[17];
    const float* fcb = (const float*)d_in[18];
    float* dout = (float*)d_out;

    float* ws = (float*)d_ws;
    size_t off = 0;
    auto alloc = [&](size_t n) { float* p = ws + off; off += n; return p; };

    float* rel = alloc(80 * 80);
    float* e = alloc((size_t)2 * N_ * E_);           // embeddings; later reused
    float* Wcat = alloc((size_t)2 * G4_ * E_);
    float* bcat = alloc(2 * G4_);
    float* Rt = alloc(512 * 512);
    float* o1 = alloc((size_t)N_ * DH2_);
    float* o2 = alloc((size_t)N_ * DH2_);
    float* u = alloc((size_t)N_ * DH2_);
    float* rowpart = alloc((size_t)40 * N_);
    float* colpart = alloc((size_t)40 * N_);
    float* rowinv = alloc(N_);
    float* colinv = alloc(N_);
    float* sf1part = alloc((size_t)80 * N_);
    float* sf1 = alloc(N_);
    float* sf2 = alloc(N_);
    float* bnmu = alloc(DF_);
    float* bnrstd = alloc(DF_);
    ushort_t* Bhi = (ushort_t*)alloc(262144);        // 512 KB
    ushort_t* Blo = (ushort_t*)alloc(262144);        // 512 KB
    ushort_t* fragbuf = (ushort_t*)alloc(131072);    // 512 KB
    int* flags = (int*)alloc(64);
    float* xg = alloc((size_t)N_ * N_);              // aliased with Ebuf
    float* Ebuf = xg;
    // split-bf16 u/t2 reuse the dead embedding buffer (exactly 2*N*E floats)
    ushort_t* uhi = (ushort_t*)e;
    ushort_t* ulo = uhi + (size_t)N_ * DH2_;
    ushort_t* vhi = ulo + (size_t)N_ * DH2_;
    ushort_t* vlo = vhi + (size_t)N_ * DH2_;

    k_rel<<<1, 256, 0, stream>>>(tE1, tE2, rel);
    k_embed<<<2 * N_, 256, 0, stream>>>(arg1, arg2, table, e);
    k_pack<<<2048, 256, 0, stream>>>(Wih_f, Wih_b, bih_f, bhh_f, bih_b, bhh_b, R,
                                     Wcat, bcat, Rt);
    k_packw<<<2048, 256, 0, stream>>>(Whh_f, Whh_b, Bhi, Blo);
    k_initlstm<<<64, 256, 0, stream>>>(fragbuf, flags);
    k_gemm<<<dim3(2 * G4_ / 64, 2 * N_ / 64), 256, 0, stream>>>(
        e, Wcat, bcat, xg, 2 * N_, 2 * G4_, E_);
    k_lstm4<<<64, 1024, 0, stream>>>(xg, Bhi, Blo, o1, o2, fragbuf, flags);
    k_gemm<<<dim3(DH2_ / 64, N_ / 64), 256, 0, stream>>>(
        o1, Rt, nullptr, u, N_, DH2_, DH2_);
    k_cvt<<<(N_ * DH2_ + 255) / 256, 256, 0, stream>>>(u, o2, uhi, ulo, vhi, vlo);
    k_bigm<<<dim3(N_ / 128, N_ / 128), 256, 0, stream>>>(
        uhi, ulo, vhi, vlo, rel, Ebuf, rowpart, colpart);
    k_redsum<<<(N_ + 255) / 256, 256, 0, stream>>>(rowpart, colpart, rowinv, colinv);
    k_sf2<<<N_, 256, 0, stream>>>(Ebuf, colinv, sf2);
    k_sf1part<<<80, 256, 0, stream>>>(Ebuf, rowinv, sf1part);
    k_sf1red<<<(N_ + 255) / 256, 256, 0, stream>>>(sf1part, sf1);
    k_bnstats<<<DF_ / 256, 256, 0, stream>>>(o1, o2, sf1, sf2, bnmu, bnrstd);
    k_logits<<<B_, 256, 0, stream>>>(o1, o2, sf1, sf2, bnmu, bnrstd, gamma, beta,
                                     fcW, fcb, dout);
}